// Round 1
// baseline (435.176 us; speedup 1.0000x reference)
//
#include <hip/hip_runtime.h>
#include <hip/hip_bf16.h>

// Mamba layer: LN -> in_proj GEMM -> conv+SiLU -> xproj GEMM -> dt GEMM+softplus
//              -> chunked selective scan -> gate -> out_proj GEMM + residual.
// All GEMMs bf16 MFMA (16x16x32), fp32 accumulate. Dims: B=2,L=2048,DM=1024,DI=2048.

typedef __attribute__((ext_vector_type(4))) float f32x4;
typedef __attribute__((ext_vector_type(8))) short s16x8;

static __device__ __forceinline__ float b2f(ushort u) {
  union { float f; unsigned int i; } v; v.i = ((unsigned int)u) << 16; return v.f;
}
static __device__ __forceinline__ ushort f2b(float f) {
  union { __hip_bfloat16 h; ushort u; } v; v.h = __float2bfloat16(f); return v.u;
}

// ---------------- casts ----------------
__global__ void cast_bf16_kernel(const float* __restrict__ src, ushort* __restrict__ dst, int n4) {
  int i = blockIdx.x * 256 + threadIdx.x;
  if (i >= n4) return;
  float4 v = ((const float4*)src)[i];
  ((ushort4*)dst)[i] = make_ushort4(f2b(v.x), f2b(v.y), f2b(v.z), f2b(v.w));
}

// W_xproj [96][2048] -> bf16 padded to [128][2048] (rows 96..127 zero)
__global__ void wxp_pad_kernel(const float* __restrict__ src, ushort* __restrict__ dst) {
  int i = blockIdx.x * 256 + threadIdx.x;   // 65536 = 128*2048/4
  int e  = i >> 9;
  int k4 = (i & 511) << 2;
  ushort4 o = make_ushort4(0, 0, 0, 0);
  if (e < 96) {
    float4 v = *(const float4*)(src + (size_t)e * 2048 + k4);
    o = make_ushort4(f2b(v.x), f2b(v.y), f2b(v.z), f2b(v.w));
  }
  ((ushort4*)dst)[i] = o;
}

// x_dbl [4096][128] cols 0..63 -> bf16 [4096][64]
__global__ void dtlow_cast_kernel(const float* __restrict__ xdbl, ushort* __restrict__ dst) {
  int i = blockIdx.x * 256 + threadIdx.x;   // 65536 = 4096*64/4
  int r  = i >> 4;
  int c4 = (i & 15) << 2;
  float4 v = *(const float4*)(xdbl + (size_t)r * 128 + c4);
  ((ushort4*)dst)[i] = make_ushort4(f2b(v.x), f2b(v.y), f2b(v.z), f2b(v.w));
}

// ---------------- layernorm -> bf16 ----------------
__global__ __launch_bounds__(256) void ln_kernel(const float* __restrict__ x,
    const float* __restrict__ w, const float* __restrict__ b, ushort* __restrict__ xn) {
  const int row = blockIdx.x;       // 4096 rows of 1024
  const int tid = threadIdx.x;
  float4 v = ((const float4*)(x + (size_t)row * 1024))[tid];
  float s  = v.x + v.y + v.z + v.w;
  float s2 = v.x*v.x + v.y*v.y + v.z*v.z + v.w*v.w;
  #pragma unroll
  for (int off = 32; off; off >>= 1) { s += __shfl_xor(s, off); s2 += __shfl_xor(s2, off); }
  __shared__ float red[8];
  if ((tid & 63) == 0) { red[tid >> 6] = s; red[(tid >> 6) + 4] = s2; }
  __syncthreads();
  float S  = red[0] + red[1] + red[2] + red[3];
  float S2 = red[4] + red[5] + red[6] + red[7];
  float mu   = S * (1.0f / 1024.0f);
  float var  = S2 * (1.0f / 1024.0f) - mu * mu;
  float rstd = rsqrtf(var + 1e-5f);
  float4 wv = ((const float4*)w)[tid];
  float4 bv = ((const float4*)b)[tid];
  ushort4 o = make_ushort4(
      f2b((v.x - mu) * rstd * wv.x + bv.x),
      f2b((v.y - mu) * rstd * wv.y + bv.y),
      f2b((v.z - mu) * rstd * wv.z + bv.z),
      f2b((v.w - mu) * rstd * wv.w + bv.w));
  ((ushort4*)(xn + (size_t)row * 1024))[tid] = o;
}

// ---------------- generic bf16 MFMA GEMM:  C[M,N] = A[M,K] * B[N,K]^T ----------------
// EPI: 1 = store bf16, 2 = atomicAdd fp32 (split-K), 3 = +bias[col] then softplus fp32,
//      4 = residual: Cf[o] = aux[o] + v
template<int EPI>
__global__ __launch_bounds__(256, 2) void gemm_bt(
    const ushort* __restrict__ A, const ushort* __restrict__ B,
    float* __restrict__ Cf, ushort* __restrict__ Cb,
    const float* __restrict__ aux,
    int M, int N, int K, int kt_per)
{
  __shared__ ushort As[128 * 40];   // +8 pad breaks b128 bank conflicts
  __shared__ ushort Bs[128 * 40];
  const int tid  = threadIdx.x;
  const int lane = tid & 63;
  const int wid  = tid >> 6;
  const int wr = wid >> 1, wc = wid & 1;
  const int m0 = blockIdx.x * 128, n0 = blockIdx.y * 128;
  const int kt0 = blockIdx.z * kt_per;

  const int r1 = tid >> 2;          // 0..63
  const int c1 = (tid & 3) << 3;    // 0,8,16,24
  const ushort* Ag0 = A + (size_t)(m0 + r1) * K + c1 + (size_t)kt0 * 32;
  const ushort* Ag1 = Ag0 + (size_t)64 * K;
  const ushort* Bg0 = B + (size_t)(n0 + r1) * K + c1 + (size_t)kt0 * 32;
  const ushort* Bg1 = Bg0 + (size_t)64 * K;

  f32x4 acc[4][4];
  #pragma unroll
  for (int m = 0; m < 4; ++m)
    #pragma unroll
    for (int n = 0; n < 4; ++n)
      acc[m][n] = (f32x4){0.f, 0.f, 0.f, 0.f};

  const int frow = lane & 15;
  const int fk   = (lane >> 4) << 3;
  const ushort* AsR = &As[(wr * 64 + frow) * 40 + fk];
  const ushort* BsR = &Bs[(wc * 64 + frow) * 40 + fk];
  ushort* Aw0 = &As[r1 * 40 + c1];
  ushort* Aw1 = &As[(r1 + 64) * 40 + c1];
  ushort* Bw0 = &Bs[r1 * 40 + c1];
  ushort* Bw1 = &Bs[(r1 + 64) * 40 + c1];

  for (int kt = 0; kt < kt_per; ++kt) {
    const size_t ko = (size_t)kt * 32;
    int4 a0 = *(const int4*)(Ag0 + ko);
    int4 a1 = *(const int4*)(Ag1 + ko);
    int4 b0 = *(const int4*)(Bg0 + ko);
    int4 b1 = *(const int4*)(Bg1 + ko);
    __syncthreads();
    *(int4*)Aw0 = a0; *(int4*)Aw1 = a1;
    *(int4*)Bw0 = b0; *(int4*)Bw1 = b1;
    __syncthreads();
    s16x8 af[4], bfr[4];
    #pragma unroll
    for (int m = 0; m < 4; ++m) af[m] = *(const s16x8*)(AsR + m * 16 * 40);
    #pragma unroll
    for (int n = 0; n < 4; ++n) bfr[n] = *(const s16x8*)(BsR + n * 16 * 40);
    #pragma unroll
    for (int m = 0; m < 4; ++m)
      #pragma unroll
      for (int n = 0; n < 4; ++n)
        acc[m][n] = __builtin_amdgcn_mfma_f32_16x16x32_bf16(af[m], bfr[n], acc[m][n], 0, 0, 0);
  }

  const int rb = m0 + wr * 64 + ((lane >> 4) << 2);
  const int cb = n0 + wc * 64 + (lane & 15);
  #pragma unroll
  for (int m = 0; m < 4; ++m) {
    #pragma unroll
    for (int n = 0; n < 4; ++n) {
      const int col = cb + n * 16;
      #pragma unroll
      for (int j = 0; j < 4; ++j) {
        const int row = rb + m * 16 + j;
        const size_t o = (size_t)row * N + col;
        float v = acc[m][n][j];
        if (EPI == 1) {
          Cb[o] = f2b(v);
        } else if (EPI == 2) {
          atomicAdd(&Cf[o], v);
        } else if (EPI == 3) {
          v += aux[col];
          Cf[o] = (v > 20.f) ? v : log1pf(__expf(v));
        } else {
          Cf[o] = aux[o] + v;
        }
      }
    }
  }
}

// ---------------- depthwise causal conv1d + SiLU ----------------
__global__ __launch_bounds__(256) void conv_silu_kernel(const ushort* __restrict__ xz,
    const float* __restrict__ cw, const float* __restrict__ cb, ushort* __restrict__ xs) {
  const int idx = blockIdx.x * 256 + threadIdx.x;  // B*L*DI = 8388608
  const int d = idx & 2047;
  const int l = (idx >> 11) & 2047;
  const int b = idx >> 22;
  float acc = cb[d];
  const float4 w4 = *(const float4*)(cw + (size_t)d * 4);
  const float wv[4] = {w4.x, w4.y, w4.z, w4.w};
  #pragma unroll
  for (int j = 0; j < 4; ++j) {
    const int ls = l - 3 + j;
    if (ls >= 0) acc += b2f(xz[((size_t)(b * 2048 + ls)) * 4096 + d]) * wv[j];
  }
  const float sv = acc / (1.f + __expf(-acc));
  xs[idx] = f2b(sv);
}

// ---------------- chunked selective scan ----------------
// Pass A: per (b, chunk, d): local scan with h0=0, store final state F + sum(dt)
__global__ __launch_bounds__(256) void scanA_kernel(const float* __restrict__ dt,
    const ushort* __restrict__ xs, const float* __restrict__ xdbl,
    const float* __restrict__ A_log, float* __restrict__ F, float* __restrict__ Sdt) {
  const int d = blockIdx.x * 256 + threadIdx.x;
  const int c = blockIdx.y, b = blockIdx.z;
  float Ad[16];
  #pragma unroll
  for (int s = 0; s < 16; ++s) Ad[s] = -__expf(A_log[(size_t)d * 16 + s]);
  float h[16];
  #pragma unroll
  for (int s = 0; s < 16; ++s) h[s] = 0.f;
  float sdt = 0.f;
  for (int il = 0; il < 128; ++il) {
    const size_t t = (size_t)b * 2048 + c * 128 + il;
    const float dtv = dt[t * 2048 + d];
    const float xv  = b2f(xs[t * 2048 + d]);
    const float dx  = dtv * xv;
    sdt += dtv;
    const float4* bc = (const float4*)(xdbl + t * 128 + 64);
    float4 B0 = bc[0], B1 = bc[1], B2 = bc[2], B3 = bc[3];
    const float Bv[16] = {B0.x, B0.y, B0.z, B0.w, B1.x, B1.y, B1.z, B1.w,
                          B2.x, B2.y, B2.z, B2.w, B3.x, B3.y, B3.z, B3.w};
    #pragma unroll
    for (int s = 0; s < 16; ++s) h[s] = __expf(dtv * Ad[s]) * h[s] + dx * Bv[s];
  }
  const size_t fo = (((size_t)b * 16 + c) * 2048 + d) * 16;
  #pragma unroll
  for (int q = 0; q < 4; ++q)
    *(float4*)(F + fo + q * 4) = make_float4(h[q*4], h[q*4+1], h[q*4+2], h[q*4+3]);
  Sdt[((size_t)b * 16 + c) * 2048 + d] = sdt;
}

// Pass B: sequential chunk combine; store initial state per chunk
__global__ __launch_bounds__(256) void scanB_kernel(const float* __restrict__ F,
    const float* __restrict__ Sdt, const float* __restrict__ A_log,
    float* __restrict__ Hinit) {
  const int idx = blockIdx.x * 256 + threadIdx.x;  // 4096 = (b,d)
  const int b = idx >> 11, d = idx & 2047;
  float Ad[16];
  #pragma unroll
  for (int s = 0; s < 16; ++s) Ad[s] = -__expf(A_log[(size_t)d * 16 + s]);
  float H[16];
  #pragma unroll
  for (int s = 0; s < 16; ++s) H[s] = 0.f;
  for (int c = 0; c < 16; ++c) {
    const size_t o = (((size_t)b * 16 + c) * 2048 + d) * 16;
    #pragma unroll
    for (int q = 0; q < 4; ++q)
      *(float4*)(Hinit + o + q * 4) = make_float4(H[q*4], H[q*4+1], H[q*4+2], H[q*4+3]);
    const float sdt = Sdt[((size_t)b * 16 + c) * 2048 + d];
    const float4* Fp = (const float4*)(F + o);
    float4 F0 = Fp[0], F1 = Fp[1], F2 = Fp[2], F3 = Fp[3];
    const float Fv[16] = {F0.x, F0.y, F0.z, F0.w, F1.x, F1.y, F1.z, F1.w,
                          F2.x, F2.y, F2.z, F2.w, F3.x, F3.y, F3.z, F3.w};
    #pragma unroll
    for (int s = 0; s < 16; ++s) H[s] = __expf(sdt * Ad[s]) * H[s] + Fv[s];
  }
}

// Pass C: recompute local scan with correct initial state; emit gated output (bf16)
__global__ __launch_bounds__(256) void scanC_kernel(const float* __restrict__ dt,
    const ushort* __restrict__ xs, const float* __restrict__ xdbl,
    const ushort* __restrict__ xz, const float* __restrict__ A_log,
    const float* __restrict__ Dskip, const float* __restrict__ Hinit,
    ushort* __restrict__ yg) {
  const int d = blockIdx.x * 256 + threadIdx.x;
  const int c = blockIdx.y, b = blockIdx.z;
  float Ad[16];
  #pragma unroll
  for (int s = 0; s < 16; ++s) Ad[s] = -__expf(A_log[(size_t)d * 16 + s]);
  float h[16];
  const size_t ho = (((size_t)b * 16 + c) * 2048 + d) * 16;
  {
    const float4* Hp = (const float4*)(Hinit + ho);
    float4 H0 = Hp[0], H1 = Hp[1], H2 = Hp[2], H3 = Hp[3];
    h[0]=H0.x; h[1]=H0.y; h[2]=H0.z; h[3]=H0.w;
    h[4]=H1.x; h[5]=H1.y; h[6]=H1.z; h[7]=H1.w;
    h[8]=H2.x; h[9]=H2.y; h[10]=H2.z; h[11]=H2.w;
    h[12]=H3.x; h[13]=H3.y; h[14]=H3.z; h[15]=H3.w;
  }
  const float Dk = Dskip[d];
  for (int il = 0; il < 128; ++il) {
    const size_t t = (size_t)b * 2048 + c * 128 + il;
    const float dtv = dt[t * 2048 + d];
    const float xv  = b2f(xs[t * 2048 + d]);
    const float dx  = dtv * xv;
    const float4* bc = (const float4*)(xdbl + t * 128 + 64);
    float4 B0 = bc[0], B1 = bc[1], B2 = bc[2], B3 = bc[3];
    float4 C0 = bc[4], C1 = bc[5], C2 = bc[6], C3 = bc[7];
    const float Bv[16] = {B0.x, B0.y, B0.z, B0.w, B1.x, B1.y, B1.z, B1.w,
                          B2.x, B2.y, B2.z, B2.w, B3.x, B3.y, B3.z, B3.w};
    const float Cv[16] = {C0.x, C0.y, C0.z, C0.w, C1.x, C1.y, C1.z, C1.w,
                          C2.x, C2.y, C2.z, C2.w, C3.x, C3.y, C3.z, C3.w};
    float y = 0.f;
    #pragma unroll
    for (int s = 0; s < 16; ++s) {
      h[s] = __expf(dtv * Ad[s]) * h[s] + dx * Bv[s];
      y += h[s] * Cv[s];
    }
    const float zv = b2f(xz[t * 4096 + 2048 + d]);
    const float g  = zv / (1.f + __expf(-zv));
    yg[t * 2048 + d] = f2b((y + xv * Dk) * g);
  }
}

// ---------------- launch ----------------
extern "C" void kernel_launch(void* const* d_in, const int* in_sizes, int n_in,
                              void* d_out, int out_size, void* d_ws, size_t ws_size,
                              hipStream_t stream) {
  (void)in_sizes; (void)n_in; (void)out_size; (void)ws_size;
  const float* x       = (const float*)d_in[0];
  const float* ln_w    = (const float*)d_in[1];
  const float* ln_b    = (const float*)d_in[2];
  const float* W_in    = (const float*)d_in[3];
  const float* conv_w  = (const float*)d_in[4];
  const float* conv_b  = (const float*)d_in[5];
  const float* W_xproj = (const float*)d_in[6];
  const float* W_dt    = (const float*)d_in[7];
  const float* b_dt    = (const float*)d_in[8];
  const float* A_log   = (const float*)d_in[9];
  const float* D_skip  = (const float*)d_in[10];
  const float* W_out   = (const float*)d_in[11];
  float* out = (float*)d_out;

  char* ws = (char*)d_ws;
  size_t off = 0;
  auto alloc = [&](size_t bytes) -> void* {
    void* p = ws + off;
    off += (bytes + 255) & ~(size_t)255;
    return p;
  };
  ushort* win_bf   = (ushort*)alloc((size_t)4096 * 1024 * 2);  //  8 MB
  ushort* wout_bf  = (ushort*)alloc((size_t)1024 * 2048 * 2);  //  4 MB
  ushort* wxp_bf   = (ushort*)alloc((size_t)128 * 2048 * 2);   //  0.5 MB
  ushort* wdt_bf   = (ushort*)alloc((size_t)2048 * 64 * 2);    //  0.25 MB
  ushort* xn_bf    = (ushort*)alloc((size_t)4096 * 1024 * 2);  //  8 MB
  ushort* xz_bf    = (ushort*)alloc((size_t)4096 * 4096 * 2);  // 32 MB
  ushort* xs_bf    = (ushort*)alloc((size_t)4096 * 2048 * 2);  // 16 MB
  float*  xdbl     = (float*)alloc((size_t)4096 * 128 * 4);    //  2 MB
  ushort* dtlow_bf = (ushort*)alloc((size_t)4096 * 64 * 2);    //  0.5 MB
  float*  dtf      = (float*)alloc((size_t)4096 * 2048 * 4);   // 32 MB
  float*  Fbuf     = (float*)alloc((size_t)65536 * 16 * 4);    //  4 MB
  float*  SdtBuf   = (float*)alloc((size_t)65536 * 4);         //  0.25 MB
  float*  Hinit    = (float*)alloc((size_t)65536 * 16 * 4);    //  4 MB
  ushort* yg_bf    = (ushort*)alloc((size_t)4096 * 2048 * 2);  // 16 MB  (total ~128 MB)

  cast_bf16_kernel<<<4096, 256, 0, stream>>>(W_in, win_bf, 4096 * 1024 / 4);
  cast_bf16_kernel<<<2048, 256, 0, stream>>>(W_out, wout_bf, 1024 * 2048 / 4);
  cast_bf16_kernel<<<128, 256, 0, stream>>>(W_dt, wdt_bf, 2048 * 64 / 4);
  wxp_pad_kernel<<<256, 256, 0, stream>>>(W_xproj, wxp_bf);

  ln_kernel<<<4096, 256, 0, stream>>>(x, ln_w, ln_b, xn_bf);

  // xz[4096,4096] = xn @ W_in^T   (bf16 out)
  gemm_bt<1><<<dim3(32, 32, 1), 256, 0, stream>>>(xn_bf, win_bf, nullptr, xz_bf, nullptr,
                                                  4096, 4096, 1024, 32);
  conv_silu_kernel<<<32768, 256, 0, stream>>>(xz_bf, conv_w, conv_b, xs_bf);

  // x_dbl[4096,128] = xs @ Wxp^T  (split-K=8, atomic fp32)
  hipMemsetAsync(xdbl, 0, (size_t)4096 * 128 * 4, stream);
  gemm_bt<2><<<dim3(32, 1, 8), 256, 0, stream>>>(xs_bf, wxp_bf, xdbl, nullptr, nullptr,
                                                 4096, 128, 2048, 8);
  dtlow_cast_kernel<<<256, 256, 0, stream>>>(xdbl, dtlow_bf);

  // dt[4096,2048] = softplus(dt_low @ W_dt^T + b_dt)
  gemm_bt<3><<<dim3(32, 16, 1), 256, 0, stream>>>(dtlow_bf, wdt_bf, dtf, nullptr, b_dt,
                                                  4096, 2048, 64, 2);

  scanA_kernel<<<dim3(8, 16, 2), 256, 0, stream>>>(dtf, xs_bf, xdbl, A_log, Fbuf, SdtBuf);
  scanB_kernel<<<16, 256, 0, stream>>>(Fbuf, SdtBuf, A_log, Hinit);
  scanC_kernel<<<dim3(8, 16, 2), 256, 0, stream>>>(dtf, xs_bf, xdbl, xz_bf, A_log, D_skip,
                                                   Hinit, yg_bf);

  // out[4096,1024] = x + yg @ W_out^T
  gemm_bt<4><<<dim3(32, 8, 1), 256, 0, stream>>>(yg_bf, wout_bf, out, nullptr, x,
                                                 4096, 1024, 2048, 64);
}

// Round 2
// 397.458 us; speedup vs baseline: 1.0949x; 1.0949x over previous
//
#include <hip/hip_runtime.h>
#include <hip/hip_bf16.h>

// Mamba layer: LN -> in_proj GEMM -> conv+SiLU -> xproj GEMM(splitK) -> dt GEMM+softplus
//              -> chunked selective scan (64 chunks) -> gate -> out_proj GEMM + residual.
// GEMMs: bf16 MFMA 16x16x32, m97 structure (global_load_lds width-16, linear LDS).

typedef __attribute__((ext_vector_type(4))) float f32x4;
typedef __attribute__((ext_vector_type(8))) short s16x8;

static __device__ __forceinline__ float b2f(ushort u) {
  union { float f; unsigned int i; } v; v.i = ((unsigned int)u) << 16; return v.f;
}
static __device__ __forceinline__ ushort f2b(float f) {
  union { __hip_bfloat16 h; ushort u; } v; v.h = __float2bfloat16(f); return v.u;
}

#define GLD16(gp, lp) __builtin_amdgcn_global_load_lds( \
    (const __attribute__((address_space(1))) void*)(gp), \
    (__attribute__((address_space(3))) void*)(lp), 16, 0, 0)

// ---------------- casts ----------------
__global__ void cast_bf16_kernel(const float* __restrict__ src, ushort* __restrict__ dst, int n4) {
  int i = blockIdx.x * 256 + threadIdx.x;
  if (i >= n4) return;
  float4 v = ((const float4*)src)[i];
  ((ushort4*)dst)[i] = make_ushort4(f2b(v.x), f2b(v.y), f2b(v.z), f2b(v.w));
}

// W_xproj [96][2048] -> bf16 padded to [128][2048] (rows 96..127 zero)
__global__ void wxp_pad_kernel(const float* __restrict__ src, ushort* __restrict__ dst) {
  int i = blockIdx.x * 256 + threadIdx.x;   // 65536 = 128*2048/4
  int e  = i >> 9;
  int k4 = (i & 511) << 2;
  ushort4 o = make_ushort4(0, 0, 0, 0);
  if (e < 96) {
    float4 v = *(const float4*)(src + (size_t)e * 2048 + k4);
    o = make_ushort4(f2b(v.x), f2b(v.y), f2b(v.z), f2b(v.w));
  }
  ((ushort4*)dst)[i] = o;
}

// ---------------- layernorm -> bf16 ----------------
__global__ __launch_bounds__(256) void ln_kernel(const float* __restrict__ x,
    const float* __restrict__ w, const float* __restrict__ b, ushort* __restrict__ xn) {
  const int row = blockIdx.x;       // 4096 rows of 1024
  const int tid = threadIdx.x;
  float4 v = ((const float4*)(x + (size_t)row * 1024))[tid];
  float s  = v.x + v.y + v.z + v.w;
  float s2 = v.x*v.x + v.y*v.y + v.z*v.z + v.w*v.w;
  #pragma unroll
  for (int off = 32; off; off >>= 1) { s += __shfl_xor(s, off); s2 += __shfl_xor(s2, off); }
  __shared__ float red[8];
  if ((tid & 63) == 0) { red[tid >> 6] = s; red[(tid >> 6) + 4] = s2; }
  __syncthreads();
  float S  = red[0] + red[1] + red[2] + red[3];
  float S2 = red[4] + red[5] + red[6] + red[7];
  float mu   = S * (1.0f / 1024.0f);
  float var  = S2 * (1.0f / 1024.0f) - mu * mu;
  float rstd = rsqrtf(var + 1e-5f);
  float4 wv = ((const float4*)w)[tid];
  float4 bv = ((const float4*)b)[tid];
  ushort4 o = make_ushort4(
      f2b((v.x - mu) * rstd * wv.x + bv.x),
      f2b((v.y - mu) * rstd * wv.y + bv.y),
      f2b((v.z - mu) * rstd * wv.z + bv.z),
      f2b((v.w - mu) * rstd * wv.w + bv.w));
  ((ushort4*)(xn + (size_t)row * 1024))[tid] = o;
}

// ---------------- bf16 MFMA GEMM (m97 structure): C[M,N] = A[M,K] * B[N,K]^T ----------
// EPI: 1 = store bf16, 2 = store fp32 slice (split-K, slice = blockIdx.z),
//      3 = +bias[col], softplus, store bf16, 4 = residual: Cf[o] = aux[o] + v
template<int EPI>
__global__ __launch_bounds__(256, 2) void gemm_lds(
    const ushort* __restrict__ A, const ushort* __restrict__ B,
    float* __restrict__ Cf, ushort* __restrict__ Cb,
    const float* __restrict__ aux,
    int M, int N, int K, int kt_per)
{
  __shared__ ushort As[128 * 32];   // linear [128][32] bf16, 8 KB
  __shared__ ushort Bs[128 * 32];
  const int tid  = threadIdx.x;
  const int lane = tid & 63;
  const int wid  = tid >> 6;
  const int wr = wid >> 1, wc = wid & 1;
  const int m0 = blockIdx.x * 128, n0 = blockIdx.y * 128;
  const int kt0 = blockIdx.z * kt_per;

  // staging: wave w covers rows w*16..w*16+15 (round 0) and +64 (round 1)
  const int srow = tid >> 2;            // 0..63
  const int scol = (tid & 3) << 3;      // 0,8,16,24 (elements)
  const ushort* Ag0 = A + (size_t)(m0 + srow) * K + scol + (size_t)kt0 * 32;
  const ushort* Ag1 = Ag0 + (size_t)64 * K;
  const ushort* Bg0 = B + (size_t)(n0 + srow) * K + scol + (size_t)kt0 * 32;
  const ushort* Bg1 = Bg0 + (size_t)64 * K;
  char* ldsA0 = (char*)As + wid * 1024;          // wave-uniform bases
  char* ldsA1 = (char*)As + 4096 + wid * 1024;
  char* ldsB0 = (char*)Bs + wid * 1024;
  char* ldsB1 = (char*)Bs + 4096 + wid * 1024;

  f32x4 acc[4][4];
  #pragma unroll
  for (int m = 0; m < 4; ++m)
    #pragma unroll
    for (int n = 0; n < 4; ++n)
      acc[m][n] = (f32x4){0.f, 0.f, 0.f, 0.f};

  const int frow = lane & 15;
  const int fk   = (lane >> 4) << 3;
  const ushort* AsR = As + (wr * 64 + frow) * 32 + fk;
  const ushort* BsR = Bs + (wc * 64 + frow) * 32 + fk;

  for (int kt = 0; kt < kt_per; ++kt) {
    const size_t ko = (size_t)kt * 32;
    GLD16(Ag0 + ko, ldsA0);
    GLD16(Ag1 + ko, ldsA1);
    GLD16(Bg0 + ko, ldsB0);
    GLD16(Bg1 + ko, ldsB1);
    __syncthreads();                 // compiler drains vmcnt before barrier
    s16x8 af[4], bfr[4];
    #pragma unroll
    for (int m = 0; m < 4; ++m) af[m] = *(const s16x8*)(AsR + m * 512);
    #pragma unroll
    for (int n = 0; n < 4; ++n) bfr[n] = *(const s16x8*)(BsR + n * 512);
    #pragma unroll
    for (int m = 0; m < 4; ++m)
      #pragma unroll
      for (int n = 0; n < 4; ++n)
        acc[m][n] = __builtin_amdgcn_mfma_f32_16x16x32_bf16(af[m], bfr[n], acc[m][n], 0, 0, 0);
    __syncthreads();                 // reads done before next-tile staging
  }

  const int rb = m0 + wr * 64 + ((lane >> 4) << 2);
  const int cb = n0 + wc * 64 + (lane & 15);
  const size_t zoff = (size_t)blockIdx.z * M * N;
  #pragma unroll
  for (int m = 0; m < 4; ++m) {
    #pragma unroll
    for (int n = 0; n < 4; ++n) {
      const int col = cb + n * 16;
      #pragma unroll
      for (int j = 0; j < 4; ++j) {
        const int row = rb + m * 16 + j;
        const size_t o = (size_t)row * N + col;
        float v = acc[m][n][j];
        if (EPI == 1) {
          Cb[o] = f2b(v);
        } else if (EPI == 2) {
          Cf[zoff + o] = v;
        } else if (EPI == 3) {
          v += aux[col];
          Cb[o] = f2b((v > 20.f) ? v : log1pf(__expf(v)));
        } else {
          Cf[o] = aux[o] + v;
        }
      }
    }
  }
}

// ---------------- depthwise causal conv1d + SiLU (4 channels/thread) --------------
__global__ __launch_bounds__(256) void conv_silu_kernel(const ushort* __restrict__ xz,
    const float* __restrict__ cw, const float* __restrict__ cb, ushort* __restrict__ xs) {
  const int idx = blockIdx.x * 256 + threadIdx.x;  // 2,097,152 = B*L*DI/4
  const int d = (idx & 511) << 2;
  const int l = (idx >> 9) & 2047;
  const int b = idx >> 20;
  float w[4][4];
  const float* cwd = cw + d * 4;
  #pragma unroll
  for (int j = 0; j < 4; ++j)
    #pragma unroll
    for (int t = 0; t < 4; ++t) w[j][t] = cwd[j * 4 + t];
  float4 acc = *(const float4*)(cb + d);
  const size_t rowb = (size_t)(b * 2048) * 4096 + d;
  #pragma unroll
  for (int t = 0; t < 4; ++t) {
    const int ls = l - 3 + t;
    if (ls >= 0) {
      ushort4 xv = *(const ushort4*)(xz + rowb + (size_t)ls * 4096);
      acc.x += b2f(xv.x) * w[0][t];
      acc.y += b2f(xv.y) * w[1][t];
      acc.z += b2f(xv.z) * w[2][t];
      acc.w += b2f(xv.w) * w[3][t];
    }
  }
  ushort4 o;
  o.x = f2b(acc.x / (1.f + __expf(-acc.x)));
  o.y = f2b(acc.y / (1.f + __expf(-acc.y)));
  o.z = f2b(acc.z / (1.f + __expf(-acc.z)));
  o.w = f2b(acc.w / (1.f + __expf(-acc.w)));
  ((ushort4*)xs)[idx] = o;
}

// ---------------- xproj split-K reduce + dtlow cast ----------------
__global__ __launch_bounds__(256) void xdbl_reduce_kernel(const float* __restrict__ x8,
    float* __restrict__ xdbl, ushort* __restrict__ dtlow) {
  const int i = blockIdx.x * 256 + threadIdx.x;  // 131072 = 4096*128/4
  const int r = i >> 5, c4 = (i & 31) << 2;
  float4 s = make_float4(0.f, 0.f, 0.f, 0.f);
  #pragma unroll
  for (int z = 0; z < 8; ++z) {
    float4 v = *(const float4*)(x8 + (size_t)z * 524288 + (size_t)r * 128 + c4);
    s.x += v.x; s.y += v.y; s.z += v.z; s.w += v.w;
  }
  *(float4*)(xdbl + (size_t)r * 128 + c4) = s;
  if (c4 < 64) {
    ((ushort4*)(dtlow + (size_t)r * 64))[c4 >> 2] =
        make_ushort4(f2b(s.x), f2b(s.y), f2b(s.z), f2b(s.w));
  }
}

// ---------------- chunked selective scan: 64 chunks of 32 ----------------
// Pass A: local scan h0=0, store final state + sum(dt) into FH/Sdt
__global__ __launch_bounds__(256) void scanA_kernel(const ushort* __restrict__ dt,
    const ushort* __restrict__ xs, const float* __restrict__ xdbl,
    const float* __restrict__ A_log, float* __restrict__ FH, float* __restrict__ Sdt) {
  const int d = blockIdx.x * 256 + threadIdx.x;
  const int c = blockIdx.y, b = blockIdx.z;
  float Ad[16];
  #pragma unroll
  for (int s = 0; s < 16; ++s) Ad[s] = -__expf(A_log[(size_t)d * 16 + s]);
  float h[16];
  #pragma unroll
  for (int s = 0; s < 16; ++s) h[s] = 0.f;
  float sdt = 0.f;
  for (int il = 0; il < 32; ++il) {
    const size_t t = (size_t)b * 2048 + c * 32 + il;
    const float dtv = b2f(dt[t * 2048 + d]);
    const float xv  = b2f(xs[t * 2048 + d]);
    const float dx  = dtv * xv;
    sdt += dtv;
    const float4* bc = (const float4*)(xdbl + t * 128 + 64);
    float4 B0 = bc[0], B1 = bc[1], B2 = bc[2], B3 = bc[3];
    const float Bv[16] = {B0.x, B0.y, B0.z, B0.w, B1.x, B1.y, B1.z, B1.w,
                          B2.x, B2.y, B2.z, B2.w, B3.x, B3.y, B3.z, B3.w};
    #pragma unroll
    for (int s = 0; s < 16; ++s) h[s] = __expf(dtv * Ad[s]) * h[s] + dx * Bv[s];
  }
  const size_t fo = (((size_t)b * 64 + c) * 2048 + d) * 16;
  #pragma unroll
  for (int q = 0; q < 4; ++q)
    *(float4*)(FH + fo + q * 4) = make_float4(h[q*4], h[q*4+1], h[q*4+2], h[q*4+3]);
  Sdt[((size_t)b * 64 + c) * 2048 + d] = sdt;
}

// Pass B: sequential chunk combine, in place (FH: final-state -> initial-state)
__global__ __launch_bounds__(256) void scanB_kernel(float* __restrict__ FH,
    const float* __restrict__ Sdt, const float* __restrict__ A_log) {
  const int idx = blockIdx.x * 256 + threadIdx.x;  // 4096 = (b,d)
  const int b = idx >> 11, d = idx & 2047;
  float Ad[16];
  #pragma unroll
  for (int s = 0; s < 16; ++s) Ad[s] = -__expf(A_log[(size_t)d * 16 + s]);
  float H[16];
  #pragma unroll
  for (int s = 0; s < 16; ++s) H[s] = 0.f;
  for (int c = 0; c < 64; ++c) {
    const size_t o = (((size_t)b * 64 + c) * 2048 + d) * 16;
    float4* Fp = (float4*)(FH + o);
    float4 F0 = Fp[0], F1 = Fp[1], F2 = Fp[2], F3 = Fp[3];
    const float Fv[16] = {F0.x, F0.y, F0.z, F0.w, F1.x, F1.y, F1.z, F1.w,
                          F2.x, F2.y, F2.z, F2.w, F3.x, F3.y, F3.z, F3.w};
    #pragma unroll
    for (int q = 0; q < 4; ++q)
      Fp[q] = make_float4(H[q*4], H[q*4+1], H[q*4+2], H[q*4+3]);
    const float sdt = Sdt[((size_t)b * 64 + c) * 2048 + d];
    #pragma unroll
    for (int s = 0; s < 16; ++s) H[s] = __expf(sdt * Ad[s]) * H[s] + Fv[s];
  }
}

// Pass C: recompute local scan from correct initial state; emit gated output (bf16)
__global__ __launch_bounds__(256) void scanC_kernel(const ushort* __restrict__ dt,
    const ushort* __restrict__ xs, const float* __restrict__ xdbl,
    const ushort* __restrict__ xz, const float* __restrict__ A_log,
    const float* __restrict__ Dskip, const float* __restrict__ FH,
    ushort* __restrict__ yg) {
  const int d = blockIdx.x * 256 + threadIdx.x;
  const int c = blockIdx.y, b = blockIdx.z;
  float Ad[16];
  #pragma unroll
  for (int s = 0; s < 16; ++s) Ad[s] = -__expf(A_log[(size_t)d * 16 + s]);
  float h[16];
  const size_t ho = (((size_t)b * 64 + c) * 2048 + d) * 16;
  {
    const float4* Hp = (const float4*)(FH + ho);
    float4 H0 = Hp[0], H1 = Hp[1], H2 = Hp[2], H3 = Hp[3];
    h[0]=H0.x; h[1]=H0.y; h[2]=H0.z; h[3]=H0.w;
    h[4]=H1.x; h[5]=H1.y; h[6]=H1.z; h[7]=H1.w;
    h[8]=H2.x; h[9]=H2.y; h[10]=H2.z; h[11]=H2.w;
    h[12]=H3.x; h[13]=H3.y; h[14]=H3.z; h[15]=H3.w;
  }
  const float Dk = Dskip[d];
  for (int il = 0; il < 32; ++il) {
    const size_t t = (size_t)b * 2048 + c * 32 + il;
    const float dtv = b2f(dt[t * 2048 + d]);
    const float xv  = b2f(xs[t * 2048 + d]);
    const float dx  = dtv * xv;
    const float4* bc = (const float4*)(xdbl + t * 128 + 64);
    float4 B0 = bc[0], B1 = bc[1], B2 = bc[2], B3 = bc[3];
    float4 C0 = bc[4], C1 = bc[5], C2 = bc[6], C3 = bc[7];
    const float Bv[16] = {B0.x, B0.y, B0.z, B0.w, B1.x, B1.y, B1.z, B1.w,
                          B2.x, B2.y, B2.z, B2.w, B3.x, B3.y, B3.z, B3.w};
    const float Cv[16] = {C0.x, C0.y, C0.z, C0.w, C1.x, C1.y, C1.z, C1.w,
                          C2.x, C2.y, C2.z, C2.w, C3.x, C3.y, C3.z, C3.w};
    float y = 0.f;
    #pragma unroll
    for (int s = 0; s < 16; ++s) {
      h[s] = __expf(dtv * Ad[s]) * h[s] + dx * Bv[s];
      y += h[s] * Cv[s];
    }
    const float zv = b2f(xz[t * 4096 + 2048 + d]);
    const float g  = zv / (1.f + __expf(-zv));
    yg[t * 2048 + d] = f2b((y + xv * Dk) * g);
  }
}

// ---------------- launch ----------------
extern "C" void kernel_launch(void* const* d_in, const int* in_sizes, int n_in,
                              void* d_out, int out_size, void* d_ws, size_t ws_size,
                              hipStream_t stream) {
  (void)in_sizes; (void)n_in; (void)out_size; (void)ws_size;
  const float* x       = (const float*)d_in[0];
  const float* ln_w    = (const float*)d_in[1];
  const float* ln_b    = (const float*)d_in[2];
  const float* W_in    = (const float*)d_in[3];
  const float* conv_w  = (const float*)d_in[4];
  const float* conv_b  = (const float*)d_in[5];
  const float* W_xproj = (const float*)d_in[6];
  const float* W_dt    = (const float*)d_in[7];
  const float* b_dt    = (const float*)d_in[8];
  const float* A_log   = (const float*)d_in[9];
  const float* D_skip  = (const float*)d_in[10];
  const float* W_out   = (const float*)d_in[11];
  float* out = (float*)d_out;

  char* ws = (char*)d_ws;
  size_t off = 0;
  auto alloc = [&](size_t bytes) -> void* {
    void* p = ws + off;
    off += (bytes + 255) & ~(size_t)255;
    return p;
  };
  ushort* win_bf   = (ushort*)alloc((size_t)4096 * 1024 * 2);  //  8 MB
  ushort* wout_bf  = (ushort*)alloc((size_t)1024 * 2048 * 2);  //  4 MB
  ushort* wxp_bf   = (ushort*)alloc((size_t)128 * 2048 * 2);   //  0.5 MB
  ushort* wdt_bf   = (ushort*)alloc((size_t)2048 * 64 * 2);    //  0.25 MB
  ushort* xn_bf    = (ushort*)alloc((size_t)4096 * 1024 * 2);  //  8 MB
  ushort* xz_bf    = (ushort*)alloc((size_t)4096 * 4096 * 2);  // 32 MB
  ushort* xs_bf    = (ushort*)alloc((size_t)4096 * 2048 * 2);  // 16 MB
  float*  xdbl     = (float*)alloc((size_t)4096 * 128 * 4);    //  2 MB
  float*  xdbl8    = (float*)alloc((size_t)8 * 4096 * 128 * 4);// 16 MB (aliased: FH after reduce)
  ushort* dtlow_bf = (ushort*)alloc((size_t)4096 * 64 * 2);    //  0.5 MB
  ushort* dtf_bf   = (ushort*)alloc((size_t)4096 * 2048 * 2);  // 16 MB (bf16 dt)
  float*  SdtBuf   = (float*)alloc((size_t)2 * 64 * 2048 * 4); //  1 MB
  ushort* yg_bf    = (ushort*)alloc((size_t)4096 * 2048 * 2);  // 16 MB  (total ~120 MB)
  float*  FH       = xdbl8;  // alias: xdbl8 dead after reduce; FH = 2*64*2048*16 f32 = 16 MB

  cast_bf16_kernel<<<4096, 256, 0, stream>>>(W_in, win_bf, 4096 * 1024 / 4);
  cast_bf16_kernel<<<2048, 256, 0, stream>>>(W_out, wout_bf, 1024 * 2048 / 4);
  cast_bf16_kernel<<<128, 256, 0, stream>>>(W_dt, wdt_bf, 2048 * 64 / 4);
  wxp_pad_kernel<<<256, 256, 0, stream>>>(W_xproj, wxp_bf);

  ln_kernel<<<4096, 256, 0, stream>>>(x, ln_w, ln_b, xn_bf);

  // xz[4096,4096] = xn @ W_in^T   (bf16 out)
  gemm_lds<1><<<dim3(32, 32, 1), 256, 0, stream>>>(xn_bf, win_bf, nullptr, xz_bf, nullptr,
                                                   4096, 4096, 1024, 32);
  conv_silu_kernel<<<8192, 256, 0, stream>>>(xz_bf, conv_w, conv_b, xs_bf);

  // x_dbl slices[8][4096][128] = xs @ Wxp^T  (split-K, non-atomic)
  gemm_lds<2><<<dim3(32, 1, 8), 256, 0, stream>>>(xs_bf, wxp_bf, xdbl8, nullptr, nullptr,
                                                  4096, 128, 2048, 8);
  xdbl_reduce_kernel<<<512, 256, 0, stream>>>(xdbl8, xdbl, dtlow_bf);

  // dt[4096,2048] = softplus(dt_low @ W_dt^T + b_dt)  (bf16 out)
  gemm_lds<3><<<dim3(32, 16, 1), 256, 0, stream>>>(dtlow_bf, wdt_bf, nullptr, dtf_bf, b_dt,
                                                   4096, 2048, 64, 2);

  scanA_kernel<<<dim3(8, 64, 2), 256, 0, stream>>>(dtf_bf, xs_bf, xdbl, A_log, FH, SdtBuf);
  scanB_kernel<<<16, 256, 0, stream>>>(FH, SdtBuf, A_log);
  scanC_kernel<<<dim3(8, 64, 2), 256, 0, stream>>>(dtf_bf, xs_bf, xdbl, xz_bf, A_log, D_skip,
                                                   FH, yg_bf);

  // out[4096,1024] = x + yg @ W_out^T
  gemm_lds<4><<<dim3(32, 8, 1), 256, 0, stream>>>(yg_bf, wout_bf, out, nullptr, x,
                                                  4096, 1024, 2048, 64);
}

// Round 3
// 364.792 us; speedup vs baseline: 1.1929x; 1.0895x over previous
//
#include <hip/hip_runtime.h>
#include <hip/hip_bf16.h>

// Mamba layer: LN -> in_proj GEMM -> conv+SiLU -> xproj GEMM(splitK) -> dt GEMM+softplus
//              -> chunked selective scan (64 chunks, state-parallel combine) -> gate
//              -> out_proj GEMM + residual.
// GEMMs: bf16 MFMA 16x16x32, m97 structure (global_load_lds width-16, linear LDS).

typedef __attribute__((ext_vector_type(4))) float f32x4;
typedef __attribute__((ext_vector_type(8))) short s16x8;

static __device__ __forceinline__ float b2f(ushort u) {
  union { float f; unsigned int i; } v; v.i = ((unsigned int)u) << 16; return v.f;
}
static __device__ __forceinline__ ushort f2b(float f) {
  union { __hip_bfloat16 h; ushort u; } v; v.h = __float2bfloat16(f); return v.u;
}

#define GLD16(gp, lp) __builtin_amdgcn_global_load_lds( \
    (const __attribute__((address_space(1))) void*)(gp), \
    (__attribute__((address_space(3))) void*)(lp), 16, 0, 0)

// ---------------- merged weight prep (all f32->bf16 casts in one dispatch) ----------
// seg0: W_in 4096x1024 ; seg1: W_out 1024x2048 ; seg2: W_dt 2048x64 ;
// seg3: W_xproj 96x2048 padded to 128x2048 (rows>=96 zero)
__global__ void prep_weights_kernel(const float* __restrict__ W_in,
    const float* __restrict__ W_out, const float* __restrict__ W_dt,
    const float* __restrict__ W_xproj, ushort* __restrict__ win,
    ushort* __restrict__ wout, ushort* __restrict__ wdt, ushort* __restrict__ wxp) {
  int i = blockIdx.x * 256 + threadIdx.x;     // float4 index
  if (i < 1048576) {
    float4 v = ((const float4*)W_in)[i];
    ((ushort4*)win)[i] = make_ushort4(f2b(v.x), f2b(v.y), f2b(v.z), f2b(v.w));
    return;
  }
  i -= 1048576;
  if (i < 524288) {
    float4 v = ((const float4*)W_out)[i];
    ((ushort4*)wout)[i] = make_ushort4(f2b(v.x), f2b(v.y), f2b(v.z), f2b(v.w));
    return;
  }
  i -= 524288;
  if (i < 32768) {
    float4 v = ((const float4*)W_dt)[i];
    ((ushort4*)wdt)[i] = make_ushort4(f2b(v.x), f2b(v.y), f2b(v.z), f2b(v.w));
    return;
  }
  i -= 32768;
  if (i < 65536) {
    int e  = i >> 9;
    int k4 = (i & 511) << 2;
    ushort4 o = make_ushort4(0, 0, 0, 0);
    if (e < 96) {
      float4 v = *(const float4*)(W_xproj + (size_t)e * 2048 + k4);
      o = make_ushort4(f2b(v.x), f2b(v.y), f2b(v.z), f2b(v.w));
    }
    ((ushort4*)wxp)[i] = o;
  }
}

// ---------------- layernorm -> bf16 ----------------
__global__ __launch_bounds__(256) void ln_kernel(const float* __restrict__ x,
    const float* __restrict__ w, const float* __restrict__ b, ushort* __restrict__ xn) {
  const int row = blockIdx.x;       // 4096 rows of 1024
  const int tid = threadIdx.x;
  float4 v = ((const float4*)(x + (size_t)row * 1024))[tid];
  float s  = v.x + v.y + v.z + v.w;
  float s2 = v.x*v.x + v.y*v.y + v.z*v.z + v.w*v.w;
  #pragma unroll
  for (int off = 32; off; off >>= 1) { s += __shfl_xor(s, off); s2 += __shfl_xor(s2, off); }
  __shared__ float red[8];
  if ((tid & 63) == 0) { red[tid >> 6] = s; red[(tid >> 6) + 4] = s2; }
  __syncthreads();
  float S  = red[0] + red[1] + red[2] + red[3];
  float S2 = red[4] + red[5] + red[6] + red[7];
  float mu   = S * (1.0f / 1024.0f);
  float var  = S2 * (1.0f / 1024.0f) - mu * mu;
  float rstd = rsqrtf(var + 1e-5f);
  float4 wv = ((const float4*)w)[tid];
  float4 bv = ((const float4*)b)[tid];
  ushort4 o = make_ushort4(
      f2b((v.x - mu) * rstd * wv.x + bv.x),
      f2b((v.y - mu) * rstd * wv.y + bv.y),
      f2b((v.z - mu) * rstd * wv.z + bv.z),
      f2b((v.w - mu) * rstd * wv.w + bv.w));
  ((ushort4*)(xn + (size_t)row * 1024))[tid] = o;
}

// ---------------- bf16 MFMA GEMM (m97 structure): C[M,N] = A[M,K] * B[N,K]^T ----------
// EPI: 1 = store bf16, 2 = store fp32 slice (split-K, slice = blockIdx.z),
//      3 = +bias[col], softplus, store bf16, 4 = residual: Cf[o] = aux[o] + v
template<int EPI>
__global__ __launch_bounds__(256, 2) void gemm_lds(
    const ushort* __restrict__ A, const ushort* __restrict__ B,
    float* __restrict__ Cf, ushort* __restrict__ Cb,
    const float* __restrict__ aux,
    int M, int N, int K, int kt_per)
{
  __shared__ ushort As[128 * 32];   // linear [128][32] bf16, 8 KB
  __shared__ ushort Bs[128 * 32];
  const int tid  = threadIdx.x;
  const int lane = tid & 63;
  const int wid  = tid >> 6;
  const int wr = wid >> 1, wc = wid & 1;
  const int m0 = blockIdx.x * 128, n0 = blockIdx.y * 128;
  const int kt0 = blockIdx.z * kt_per;

  const int srow = tid >> 2;            // 0..63
  const int scol = (tid & 3) << 3;      // 0,8,16,24 (elements)
  const ushort* Ag0 = A + (size_t)(m0 + srow) * K + scol + (size_t)kt0 * 32;
  const ushort* Ag1 = Ag0 + (size_t)64 * K;
  const ushort* Bg0 = B + (size_t)(n0 + srow) * K + scol + (size_t)kt0 * 32;
  const ushort* Bg1 = Bg0 + (size_t)64 * K;
  char* ldsA0 = (char*)As + wid * 1024;          // wave-uniform bases
  char* ldsA1 = (char*)As + 4096 + wid * 1024;
  char* ldsB0 = (char*)Bs + wid * 1024;
  char* ldsB1 = (char*)Bs + 4096 + wid * 1024;

  f32x4 acc[4][4];
  #pragma unroll
  for (int m = 0; m < 4; ++m)
    #pragma unroll
    for (int n = 0; n < 4; ++n)
      acc[m][n] = (f32x4){0.f, 0.f, 0.f, 0.f};

  const int frow = lane & 15;
  const int fk   = (lane >> 4) << 3;
  const ushort* AsR = As + (wr * 64 + frow) * 32 + fk;
  const ushort* BsR = Bs + (wc * 64 + frow) * 32 + fk;

  for (int kt = 0; kt < kt_per; ++kt) {
    const size_t ko = (size_t)kt * 32;
    GLD16(Ag0 + ko, ldsA0);
    GLD16(Ag1 + ko, ldsA1);
    GLD16(Bg0 + ko, ldsB0);
    GLD16(Bg1 + ko, ldsB1);
    __syncthreads();
    s16x8 af[4], bfr[4];
    #pragma unroll
    for (int m = 0; m < 4; ++m) af[m] = *(const s16x8*)(AsR + m * 512);
    #pragma unroll
    for (int n = 0; n < 4; ++n) bfr[n] = *(const s16x8*)(BsR + n * 512);
    #pragma unroll
    for (int m = 0; m < 4; ++m)
      #pragma unroll
      for (int n = 0; n < 4; ++n)
        acc[m][n] = __builtin_amdgcn_mfma_f32_16x16x32_bf16(af[m], bfr[n], acc[m][n], 0, 0, 0);
    __syncthreads();
  }

  const int rb = m0 + wr * 64 + ((lane >> 4) << 2);
  const int cb = n0 + wc * 64 + (lane & 15);
  const size_t zoff = (size_t)blockIdx.z * M * N;
  #pragma unroll
  for (int m = 0; m < 4; ++m) {
    #pragma unroll
    for (int n = 0; n < 4; ++n) {
      const int col = cb + n * 16;
      #pragma unroll
      for (int j = 0; j < 4; ++j) {
        const int row = rb + m * 16 + j;
        const size_t o = (size_t)row * N + col;
        float v = acc[m][n][j];
        if (EPI == 1) {
          Cb[o] = f2b(v);
        } else if (EPI == 2) {
          Cf[zoff + o] = v;
        } else if (EPI == 3) {
          v += aux[col];
          Cb[o] = f2b((v > 20.f) ? v : log1pf(__expf(v)));
        } else {
          Cf[o] = aux[o] + v;
        }
      }
    }
  }
}

// ---------------- depthwise causal conv1d + SiLU (4 channels/thread) --------------
__global__ __launch_bounds__(256) void conv_silu_kernel(const ushort* __restrict__ xz,
    const float* __restrict__ cw, const float* __restrict__ cb, ushort* __restrict__ xs) {
  const int idx = blockIdx.x * 256 + threadIdx.x;  // 2,097,152 = B*L*DI/4
  const int d = (idx & 511) << 2;
  const int l = (idx >> 9) & 2047;
  const int b = idx >> 20;
  float w[4][4];
  const float* cwd = cw + d * 4;
  #pragma unroll
  for (int j = 0; j < 4; ++j)
    #pragma unroll
    for (int t = 0; t < 4; ++t) w[j][t] = cwd[j * 4 + t];
  float4 acc = *(const float4*)(cb + d);
  const size_t rowb = (size_t)(b * 2048) * 4096 + d;
  #pragma unroll
  for (int t = 0; t < 4; ++t) {
    const int ls = l - 3 + t;
    if (ls >= 0) {
      ushort4 xv = *(const ushort4*)(xz + rowb + (size_t)ls * 4096);
      acc.x += b2f(xv.x) * w[0][t];
      acc.y += b2f(xv.y) * w[1][t];
      acc.z += b2f(xv.z) * w[2][t];
      acc.w += b2f(xv.w) * w[3][t];
    }
  }
  ushort4 o;
  o.x = f2b(acc.x / (1.f + __expf(-acc.x)));
  o.y = f2b(acc.y / (1.f + __expf(-acc.y)));
  o.z = f2b(acc.z / (1.f + __expf(-acc.z)));
  o.w = f2b(acc.w / (1.f + __expf(-acc.w)));
  ((ushort4*)xs)[idx] = o;
}

// ---------------- xproj split-K reduce + dtlow cast ----------------
__global__ __launch_bounds__(256) void xdbl_reduce_kernel(const float* __restrict__ x8,
    float* __restrict__ xdbl, ushort* __restrict__ dtlow) {
  const int i = blockIdx.x * 256 + threadIdx.x;  // 131072 = 4096*128/4
  const int r = i >> 5, c4 = (i & 31) << 2;
  float4 s = make_float4(0.f, 0.f, 0.f, 0.f);
  #pragma unroll
  for (int z = 0; z < 8; ++z) {
    float4 v = *(const float4*)(x8 + (size_t)z * 524288 + (size_t)r * 128 + c4);
    s.x += v.x; s.y += v.y; s.z += v.z; s.w += v.w;
  }
  *(float4*)(xdbl + (size_t)r * 128 + c4) = s;
  if (c4 < 64) {
    ((ushort4*)(dtlow + (size_t)r * 64))[c4 >> 2] =
        make_ushort4(f2b(s.x), f2b(s.y), f2b(s.z), f2b(s.w));
  }
}

// ---------------- chunked selective scan: 64 chunks of 32 ----------------
// Pass A: local scan h0=0, store final state + sum(dt). B staged in LDS.
__global__ __launch_bounds__(256, 4) void scanA_kernel(const ushort* __restrict__ dt,
    const ushort* __restrict__ xs, const float* __restrict__ xdbl,
    const float* __restrict__ A_log, float* __restrict__ FH, float* __restrict__ Sdt) {
  __shared__ float Bsh[32 * 16];
  const int tid = threadIdx.x;
  const int d = blockIdx.x * 256 + tid;
  const int c = blockIdx.y, b = blockIdx.z;
  const int t0 = b * 2048 + c * 32;
  if (tid < 128) {
    const int il = tid >> 2, q = (tid & 3) << 2;
    *(float4*)&Bsh[il * 16 + q] = *(const float4*)(xdbl + (size_t)(t0 + il) * 128 + 64 + q);
  }
  float Ad[16];
  #pragma unroll
  for (int s = 0; s < 16; ++s) Ad[s] = -__expf(A_log[(size_t)d * 16 + s]);
  __syncthreads();
  float h[16];
  #pragma unroll
  for (int s = 0; s < 16; ++s) h[s] = 0.f;
  float sdt = 0.f;
  const ushort* dtp = dt + (size_t)t0 * 2048 + d;
  const ushort* xsp = xs + (size_t)t0 * 2048 + d;
  float dtv = b2f(dtp[0]);
  float xv  = b2f(xsp[0]);
  for (int il = 0; il < 32; ++il) {
    float dtn = 0.f, xn = 0.f;
    if (il < 31) { dtn = b2f(dtp[(il + 1) * 2048]); xn = b2f(xsp[(il + 1) * 2048]); }
    const float dx = dtv * xv;
    sdt += dtv;
    const float* Bv = &Bsh[il * 16];
    #pragma unroll
    for (int s = 0; s < 16; ++s) h[s] = __expf(dtv * Ad[s]) * h[s] + dx * Bv[s];
    dtv = dtn; xv = xn;
  }
  const size_t fo = (((size_t)b * 64 + c) * 2048 + d) * 16;
  #pragma unroll
  for (int q = 0; q < 4; ++q)
    *(float4*)(FH + fo + q * 4) = make_float4(h[q*4], h[q*4+1], h[q*4+2], h[q*4+3]);
  Sdt[((size_t)b * 64 + c) * 2048 + d] = sdt;
}

// Pass B: chunk combine, state-parallel: thread per (b,d,s). In place FH: F -> Hinit.
__global__ __launch_bounds__(256) void scanB_kernel(float* __restrict__ FH,
    const float* __restrict__ Sdt, const float* __restrict__ A_log) {
  const int idx = blockIdx.x * 256 + threadIdx.x;  // 65536 = (b,d,s)
  const int s = idx & 15;
  const int d = (idx >> 4) & 2047;
  const int b = idx >> 15;
  const float Ad = -__expf(A_log[(size_t)d * 16 + s]);
  float H = 0.f;
  #pragma unroll 8
  for (int c = 0; c < 64; ++c) {
    const size_t o = (((size_t)b * 64 + c) * 2048 + d) * 16 + s;
    const float F   = FH[o];
    const float sdt = Sdt[((size_t)b * 64 + c) * 2048 + d];
    FH[o] = H;
    H = __expf(sdt * Ad) * H + F;
  }
}

// Pass C: recompute local scan from initial state; emit gated output. B,C staged in LDS.
__global__ __launch_bounds__(256, 4) void scanC_kernel(const ushort* __restrict__ dt,
    const ushort* __restrict__ xs, const float* __restrict__ xdbl,
    const ushort* __restrict__ xz, const float* __restrict__ A_log,
    const float* __restrict__ Dskip, const float* __restrict__ FH,
    ushort* __restrict__ yg) {
  __shared__ float BCsh[32 * 32];
  const int tid = threadIdx.x;
  const int d = blockIdx.x * 256 + tid;
  const int c = blockIdx.y, b = blockIdx.z;
  const int t0 = b * 2048 + c * 32;
  {
    const int il = tid >> 3, q = (tid & 7) << 2;
    *(float4*)&BCsh[il * 32 + q] = *(const float4*)(xdbl + (size_t)(t0 + il) * 128 + 64 + q);
  }
  float Ad[16];
  #pragma unroll
  for (int s = 0; s < 16; ++s) Ad[s] = -__expf(A_log[(size_t)d * 16 + s]);
  float h[16];
  const size_t ho = (((size_t)b * 64 + c) * 2048 + d) * 16;
  {
    const float4* Hp = (const float4*)(FH + ho);
    float4 H0 = Hp[0], H1 = Hp[1], H2 = Hp[2], H3 = Hp[3];
    h[0]=H0.x; h[1]=H0.y; h[2]=H0.z; h[3]=H0.w;
    h[4]=H1.x; h[5]=H1.y; h[6]=H1.z; h[7]=H1.w;
    h[8]=H2.x; h[9]=H2.y; h[10]=H2.z; h[11]=H2.w;
    h[12]=H3.x; h[13]=H3.y; h[14]=H3.z; h[15]=H3.w;
  }
  __syncthreads();
  const float Dk = Dskip[d];
  const ushort* dtp = dt + (size_t)t0 * 2048 + d;
  const ushort* xsp = xs + (size_t)t0 * 2048 + d;
  const ushort* zp  = xz + (size_t)t0 * 4096 + 2048 + d;
  ushort* ygp = yg + (size_t)t0 * 2048 + d;
  float dtv = b2f(dtp[0]);
  float xv  = b2f(xsp[0]);
  float zv  = b2f(zp[0]);
  for (int il = 0; il < 32; ++il) {
    float dtn = 0.f, xn = 0.f, zn = 0.f;
    if (il < 31) {
      dtn = b2f(dtp[(il + 1) * 2048]);
      xn  = b2f(xsp[(il + 1) * 2048]);
      zn  = b2f(zp[(size_t)(il + 1) * 4096]);
    }
    const float dx = dtv * xv;
    const float* Bv = &BCsh[il * 32];
    const float* Cv = &BCsh[il * 32 + 16];
    float y = 0.f;
    #pragma unroll
    for (int s = 0; s < 16; ++s) {
      h[s] = __expf(dtv * Ad[s]) * h[s] + dx * Bv[s];
      y += h[s] * Cv[s];
    }
    const float g = zv / (1.f + __expf(-zv));
    ygp[il * 2048] = f2b((y + xv * Dk) * g);
    dtv = dtn; xv = xn; zv = zn;
  }
}

// ---------------- launch ----------------
extern "C" void kernel_launch(void* const* d_in, const int* in_sizes, int n_in,
                              void* d_out, int out_size, void* d_ws, size_t ws_size,
                              hipStream_t stream) {
  (void)in_sizes; (void)n_in; (void)out_size; (void)ws_size;
  const float* x       = (const float*)d_in[0];
  const float* ln_w    = (const float*)d_in[1];
  const float* ln_b    = (const float*)d_in[2];
  const float* W_in    = (const float*)d_in[3];
  const float* conv_w  = (const float*)d_in[4];
  const float* conv_b  = (const float*)d_in[5];
  const float* W_xproj = (const float*)d_in[6];
  const float* W_dt    = (const float*)d_in[7];
  const float* b_dt    = (const float*)d_in[8];
  const float* A_log   = (const float*)d_in[9];
  const float* D_skip  = (const float*)d_in[10];
  const float* W_out   = (const float*)d_in[11];
  float* out = (float*)d_out;

  char* ws = (char*)d_ws;
  size_t off = 0;
  auto alloc = [&](size_t bytes) -> void* {
    void* p = ws + off;
    off += (bytes + 255) & ~(size_t)255;
    return p;
  };
  ushort* win_bf   = (ushort*)alloc((size_t)4096 * 1024 * 2);  //  8 MB
  ushort* wout_bf  = (ushort*)alloc((size_t)1024 * 2048 * 2);  //  4 MB
  ushort* wxp_bf   = (ushort*)alloc((size_t)128 * 2048 * 2);   //  0.5 MB
  ushort* wdt_bf   = (ushort*)alloc((size_t)2048 * 64 * 2);    //  0.25 MB
  ushort* xn_bf    = (ushort*)alloc((size_t)4096 * 1024 * 2);  //  8 MB
  ushort* xz_bf    = (ushort*)alloc((size_t)4096 * 4096 * 2);  // 32 MB
  ushort* xs_bf    = (ushort*)alloc((size_t)4096 * 2048 * 2);  // 16 MB
  float*  xdbl     = (float*)alloc((size_t)4096 * 128 * 4);    //  2 MB
  float*  xdbl8    = (float*)alloc((size_t)8 * 4096 * 128 * 4);// 16 MB (aliased: FH after reduce)
  ushort* dtlow_bf = (ushort*)alloc((size_t)4096 * 64 * 2);    //  0.5 MB
  ushort* dtf_bf   = (ushort*)alloc((size_t)4096 * 2048 * 2);  // 16 MB (bf16 dt)
  float*  SdtBuf   = (float*)alloc((size_t)2 * 64 * 2048 * 4); //  1 MB
  ushort* yg_bf    = (ushort*)alloc((size_t)4096 * 2048 * 2);  // 16 MB  (total ~120 MB)
  float*  FH       = xdbl8;  // alias: xdbl8 dead after reduce; FH = 2*64*2048*16 f32 = 16 MB

  prep_weights_kernel<<<6528, 256, 0, stream>>>(W_in, W_out, W_dt, W_xproj,
                                                win_bf, wout_bf, wdt_bf, wxp_bf);
  ln_kernel<<<4096, 256, 0, stream>>>(x, ln_w, ln_b, xn_bf);

  // xz[4096,4096] = xn @ W_in^T   (bf16 out)
  gemm_lds<1><<<dim3(32, 32, 1), 256, 0, stream>>>(xn_bf, win_bf, nullptr, xz_bf, nullptr,
                                                   4096, 4096, 1024, 32);
  conv_silu_kernel<<<8192, 256, 0, stream>>>(xz_bf, conv_w, conv_b, xs_bf);

  // x_dbl slices[8][4096][128] = xs @ Wxp^T  (split-K, non-atomic)
  gemm_lds<2><<<dim3(32, 1, 8), 256, 0, stream>>>(xs_bf, wxp_bf, xdbl8, nullptr, nullptr,
                                                  4096, 128, 2048, 8);
  xdbl_reduce_kernel<<<512, 256, 0, stream>>>(xdbl8, xdbl, dtlow_bf);

  // dt[4096,2048] = softplus(dt_low @ W_dt^T + b_dt)  (bf16 out)
  gemm_lds<3><<<dim3(32, 16, 1), 256, 0, stream>>>(dtlow_bf, wdt_bf, nullptr, dtf_bf, b_dt,
                                                   4096, 2048, 64, 2);

  scanA_kernel<<<dim3(8, 64, 2), 256, 0, stream>>>(dtf_bf, xs_bf, xdbl, A_log, FH, SdtBuf);
  scanB_kernel<<<256, 256, 0, stream>>>(FH, SdtBuf, A_log);
  scanC_kernel<<<dim3(8, 64, 2), 256, 0, stream>>>(dtf_bf, xs_bf, xdbl, xz_bf, A_log, D_skip,
                                                   FH, yg_bf);

  // out[4096,1024] = x + yg @ W_out^T
  gemm_lds<4><<<dim3(32, 8, 1), 256, 0, stream>>>(yg_bf, wout_bf, out, nullptr, x,
                                                  4096, 1024, 2048, 64);
}

// Round 4
// 326.291 us; speedup vs baseline: 1.3337x; 1.1180x over previous
//
#include <hip/hip_runtime.h>
#include <hip/hip_bf16.h>

// Mamba layer: LN -> in_proj GEMM -> conv+SiLU -> xproj GEMM(splitK) -> dt GEMM+softplus
//              -> chunked selective scan (64 chunks, state-parallel combine) -> gate
//              -> out_proj GEMM + residual.
// GEMMs: bf16 MFMA 16x16x32, m97 staging (global_load_lds width-16, linear LDS),
//        coalesced epilogue via LDS bounce (4 phases x 32 rows, stride-130 f32).

typedef __attribute__((ext_vector_type(4))) float f32x4;
typedef __attribute__((ext_vector_type(8))) short s16x8;

static __device__ __forceinline__ float b2f(ushort u) {
  union { float f; unsigned int i; } v; v.i = ((unsigned int)u) << 16; return v.f;
}
static __device__ __forceinline__ ushort f2b(float f) {
  union { __hip_bfloat16 h; ushort u; } v; v.h = __float2bfloat16(f); return v.u;
}

#define GLD16(gp, lp) __builtin_amdgcn_global_load_lds( \
    (const __attribute__((address_space(1))) void*)(gp), \
    (__attribute__((address_space(3))) void*)(lp), 16, 0, 0)

// ---------------- merged weight prep (all f32->bf16 casts in one dispatch) ----------
__global__ void prep_weights_kernel(const float* __restrict__ W_in,
    const float* __restrict__ W_out, const float* __restrict__ W_dt,
    const float* __restrict__ W_xproj, ushort* __restrict__ win,
    ushort* __restrict__ wout, ushort* __restrict__ wdt, ushort* __restrict__ wxp) {
  int i = blockIdx.x * 256 + threadIdx.x;     // float4 index
  if (i < 1048576) {
    float4 v = ((const float4*)W_in)[i];
    ((ushort4*)win)[i] = make_ushort4(f2b(v.x), f2b(v.y), f2b(v.z), f2b(v.w));
    return;
  }
  i -= 1048576;
  if (i < 524288) {
    float4 v = ((const float4*)W_out)[i];
    ((ushort4*)wout)[i] = make_ushort4(f2b(v.x), f2b(v.y), f2b(v.z), f2b(v.w));
    return;
  }
  i -= 524288;
  if (i < 32768) {
    float4 v = ((const float4*)W_dt)[i];
    ((ushort4*)wdt)[i] = make_ushort4(f2b(v.x), f2b(v.y), f2b(v.z), f2b(v.w));
    return;
  }
  i -= 32768;
  if (i < 65536) {
    int e  = i >> 9;
    int k4 = (i & 511) << 2;
    ushort4 o = make_ushort4(0, 0, 0, 0);
    if (e < 96) {
      float4 v = *(const float4*)(W_xproj + (size_t)e * 2048 + k4);
      o = make_ushort4(f2b(v.x), f2b(v.y), f2b(v.z), f2b(v.w));
    }
    ((ushort4*)wxp)[i] = o;
  }
}

// ---------------- layernorm -> bf16 ----------------
__global__ __launch_bounds__(256) void ln_kernel(const float* __restrict__ x,
    const float* __restrict__ w, const float* __restrict__ b, ushort* __restrict__ xn) {
  const int row = blockIdx.x;       // 4096 rows of 1024
  const int tid = threadIdx.x;
  float4 v = ((const float4*)(x + (size_t)row * 1024))[tid];
  float s  = v.x + v.y + v.z + v.w;
  float s2 = v.x*v.x + v.y*v.y + v.z*v.z + v.w*v.w;
  #pragma unroll
  for (int off = 32; off; off >>= 1) { s += __shfl_xor(s, off); s2 += __shfl_xor(s2, off); }
  __shared__ float red[8];
  if ((tid & 63) == 0) { red[tid >> 6] = s; red[(tid >> 6) + 4] = s2; }
  __syncthreads();
  float S  = red[0] + red[1] + red[2] + red[3];
  float S2 = red[4] + red[5] + red[6] + red[7];
  float mu   = S * (1.0f / 1024.0f);
  float var  = S2 * (1.0f / 1024.0f) - mu * mu;
  float rstd = rsqrtf(var + 1e-5f);
  float4 wv = ((const float4*)w)[tid];
  float4 bv = ((const float4*)b)[tid];
  ushort4 o = make_ushort4(
      f2b((v.x - mu) * rstd * wv.x + bv.x),
      f2b((v.y - mu) * rstd * wv.y + bv.y),
      f2b((v.z - mu) * rstd * wv.z + bv.z),
      f2b((v.w - mu) * rstd * wv.w + bv.w));
  ((ushort4*)(xn + (size_t)row * 1024))[tid] = o;
}

// ---------------- bf16 MFMA GEMM: C[M,N] = A[M,K] * B[N,K]^T ----------
// EPI: 1 = store bf16, 2 = store fp32 slice (split-K, slice = blockIdx.z),
//      3 = +bias[col], softplus, store bf16, 4 = residual: Cf[o] = aux[o] + v
template<int EPI>
__global__ __launch_bounds__(256, 2) void gemm_lds(
    const ushort* __restrict__ A, const ushort* __restrict__ B,
    float* __restrict__ Cf, ushort* __restrict__ Cb,
    const float* __restrict__ aux,
    int M, int N, int K, int kt_per)
{
  __shared__ __align__(16) char SM[16640];     // As(8K) + Bs(8K); reused as epi 32x130 f32
  ushort* As = (ushort*)SM;
  ushort* Bs = (ushort*)(SM + 8192);
  float*  epi = (float*)SM;
  const int tid  = threadIdx.x;
  const int lane = tid & 63;
  const int wid  = tid >> 6;
  const int wr = wid >> 1, wc = wid & 1;
  const int m0 = blockIdx.x * 128, n0 = blockIdx.y * 128;
  const int kt0 = blockIdx.z * kt_per;

  const int srow = tid >> 2;            // 0..63
  const int scol = (tid & 3) << 3;      // 0,8,16,24 (elements)
  const ushort* Ag0 = A + (size_t)(m0 + srow) * K + scol + (size_t)kt0 * 32;
  const ushort* Ag1 = Ag0 + (size_t)64 * K;
  const ushort* Bg0 = B + (size_t)(n0 + srow) * K + scol + (size_t)kt0 * 32;
  const ushort* Bg1 = Bg0 + (size_t)64 * K;
  char* ldsA0 = (char*)As + wid * 1024;          // wave-uniform bases
  char* ldsA1 = (char*)As + 4096 + wid * 1024;
  char* ldsB0 = (char*)Bs + wid * 1024;
  char* ldsB1 = (char*)Bs + 4096 + wid * 1024;

  f32x4 acc[4][4];
  #pragma unroll
  for (int m = 0; m < 4; ++m)
    #pragma unroll
    for (int n = 0; n < 4; ++n)
      acc[m][n] = (f32x4){0.f, 0.f, 0.f, 0.f};

  const int frow = lane & 15;
  const int fk   = (lane >> 4) << 3;
  const ushort* AsR = As + (wr * 64 + frow) * 32 + fk;
  const ushort* BsR = Bs + (wc * 64 + frow) * 32 + fk;

  for (int kt = 0; kt < kt_per; ++kt) {
    const size_t ko = (size_t)kt * 32;
    GLD16(Ag0 + ko, ldsA0);
    GLD16(Ag1 + ko, ldsA1);
    GLD16(Bg0 + ko, ldsB0);
    GLD16(Bg1 + ko, ldsB1);
    __syncthreads();
    s16x8 af[4], bfr[4];
    #pragma unroll
    for (int m = 0; m < 4; ++m) af[m] = *(const s16x8*)(AsR + m * 512);
    #pragma unroll
    for (int n = 0; n < 4; ++n) bfr[n] = *(const s16x8*)(BsR + n * 512);
    #pragma unroll
    for (int m = 0; m < 4; ++m)
      #pragma unroll
      for (int n = 0; n < 4; ++n)
        acc[m][n] = __builtin_amdgcn_mfma_f32_16x16x32_bf16(af[m], bfr[n], acc[m][n], 0, 0, 0);
    __syncthreads();
  }

  // ---- coalesced epilogue: 4 phases of 32 rows through LDS ----
  const int rl = tid >> 3;              // 0..31  (band row)
  const int c0 = (tid & 7) << 4;        // 0,16,...,112
  const size_t zoff = (EPI == 2) ? (size_t)blockIdx.z * M * N : 0;
  #pragma unroll
  for (int m = 0; m < 4; ++m) {
    // write acc fragments for this m-phase
    #pragma unroll
    for (int n = 0; n < 4; ++n) {
      const int cl = wc * 64 + n * 16 + (lane & 15);
      #pragma unroll
      for (int j = 0; j < 4; ++j) {
        const int rr = wr * 16 + ((lane >> 4) << 2) + j;
        epi[rr * 130 + cl] = acc[m][n][j];
      }
    }
    __syncthreads();
    // store 32 rows x 128 cols, 16 contiguous cols per thread
    const int grow = m0 + ((rl >> 4) << 6) + m * 16 + (rl & 15);
    const int gcol = n0 + c0;
    float v[16];
    #pragma unroll
    for (int q = 0; q < 16; ++q) v[q] = epi[rl * 130 + c0 + q];
    if (EPI == 1) {
      ushort u[16];
      #pragma unroll
      for (int q = 0; q < 16; ++q) u[q] = f2b(v[q]);
      *(int4*)(Cb + (size_t)grow * N + gcol)     = *(int4*)&u[0];
      *(int4*)(Cb + (size_t)grow * N + gcol + 8) = *(int4*)&u[8];
    } else if (EPI == 2) {
      #pragma unroll
      for (int q = 0; q < 4; ++q)
        *(float4*)(Cf + zoff + (size_t)grow * N + gcol + q * 4) = *(float4*)&v[q * 4];
    } else if (EPI == 3) {
      ushort u[16];
      #pragma unroll
      for (int q = 0; q < 4; ++q) {
        float4 bb = *(const float4*)(aux + gcol + q * 4);
        float t0 = v[q*4+0] + bb.x, t1 = v[q*4+1] + bb.y;
        float t2 = v[q*4+2] + bb.z, t3 = v[q*4+3] + bb.w;
        // softplus(v) = max(v,0) + log(1+exp(-|v|))  (exact, branch-free)
        u[q*4+0] = f2b(fmaxf(t0, 0.f) + __logf(1.f + __expf(-fabsf(t0))));
        u[q*4+1] = f2b(fmaxf(t1, 0.f) + __logf(1.f + __expf(-fabsf(t1))));
        u[q*4+2] = f2b(fmaxf(t2, 0.f) + __logf(1.f + __expf(-fabsf(t2))));
        u[q*4+3] = f2b(fmaxf(t3, 0.f) + __logf(1.f + __expf(-fabsf(t3))));
      }
      *(int4*)(Cb + (size_t)grow * N + gcol)     = *(int4*)&u[0];
      *(int4*)(Cb + (size_t)grow * N + gcol + 8) = *(int4*)&u[8];
    } else {
      #pragma unroll
      for (int q = 0; q < 4; ++q) {
        float4 rr = *(const float4*)(aux + (size_t)grow * N + gcol + q * 4);
        float4 ov = make_float4(rr.x + v[q*4+0], rr.y + v[q*4+1],
                                rr.z + v[q*4+2], rr.w + v[q*4+3]);
        *(float4*)(Cf + (size_t)grow * N + gcol + q * 4) = ov;
      }
    }
    __syncthreads();
  }
}

// ---------------- depthwise causal conv1d + SiLU (4 channels/thread) --------------
__global__ __launch_bounds__(256) void conv_silu_kernel(const ushort* __restrict__ xz,
    const float* __restrict__ cw, const float* __restrict__ cb, ushort* __restrict__ xs) {
  const int idx = blockIdx.x * 256 + threadIdx.x;  // 2,097,152 = B*L*DI/4
  const int d = (idx & 511) << 2;
  const int l = (idx >> 9) & 2047;
  const int b = idx >> 20;
  float w[4][4];
  const float* cwd = cw + d * 4;
  #pragma unroll
  for (int j = 0; j < 4; ++j)
    #pragma unroll
    for (int t = 0; t < 4; ++t) w[j][t] = cwd[j * 4 + t];
  float4 acc = *(const float4*)(cb + d);
  const size_t rowb = (size_t)(b * 2048) * 4096 + d;
  #pragma unroll
  for (int t = 0; t < 4; ++t) {
    const int ls = l - 3 + t;
    if (ls >= 0) {
      ushort4 xv = *(const ushort4*)(xz + rowb + (size_t)ls * 4096);
      acc.x += b2f(xv.x) * w[0][t];
      acc.y += b2f(xv.y) * w[1][t];
      acc.z += b2f(xv.z) * w[2][t];
      acc.w += b2f(xv.w) * w[3][t];
    }
  }
  ushort4 o;
  o.x = f2b(acc.x / (1.f + __expf(-acc.x)));
  o.y = f2b(acc.y / (1.f + __expf(-acc.y)));
  o.z = f2b(acc.z / (1.f + __expf(-acc.z)));
  o.w = f2b(acc.w / (1.f + __expf(-acc.w)));
  ((ushort4*)xs)[idx] = o;
}

// ---------------- xproj split-K reduce + dtlow cast ----------------
__global__ __launch_bounds__(256) void xdbl_reduce_kernel(const float* __restrict__ x8,
    float* __restrict__ xdbl, ushort* __restrict__ dtlow) {
  const int i = blockIdx.x * 256 + threadIdx.x;  // 131072 = 4096*128/4
  const int r = i >> 5, c4 = (i & 31) << 2;
  float4 s = make_float4(0.f, 0.f, 0.f, 0.f);
  #pragma unroll
  for (int z = 0; z < 8; ++z) {
    float4 v = *(const float4*)(x8 + (size_t)z * 524288 + (size_t)r * 128 + c4);
    s.x += v.x; s.y += v.y; s.z += v.z; s.w += v.w;
  }
  *(float4*)(xdbl + (size_t)r * 128 + c4) = s;
  if (c4 < 64) {
    ((ushort4*)(dtlow + (size_t)r * 64))[c4 >> 2] =
        make_ushort4(f2b(s.x), f2b(s.y), f2b(s.z), f2b(s.w));
  }
}

// ---------------- chunked selective scan: 64 chunks of 32 ----------------
// Pass A: local scan h0=0, store final state + sum(dt). B staged in LDS.
__global__ __launch_bounds__(256, 4) void scanA_kernel(const ushort* __restrict__ dt,
    const ushort* __restrict__ xs, const float* __restrict__ xdbl,
    const float* __restrict__ A_log, float* __restrict__ FH, float* __restrict__ Sdt) {
  __shared__ float Bsh[32 * 16];
  const int tid = threadIdx.x;
  const int d = blockIdx.x * 256 + tid;
  const int c = blockIdx.y, b = blockIdx.z;
  const int t0 = b * 2048 + c * 32;
  if (tid < 128) {
    const int il = tid >> 2, q = (tid & 3) << 2;
    *(float4*)&Bsh[il * 16 + q] = *(const float4*)(xdbl + (size_t)(t0 + il) * 128 + 64 + q);
  }
  float Ad[16];
  #pragma unroll
  for (int s = 0; s < 16; ++s) Ad[s] = -__expf(A_log[(size_t)d * 16 + s]);
  __syncthreads();
  float h[16];
  #pragma unroll
  for (int s = 0; s < 16; ++s) h[s] = 0.f;
  float sdt = 0.f;
  const ushort* dtp = dt + (size_t)t0 * 2048 + d;
  const ushort* xsp = xs + (size_t)t0 * 2048 + d;
  float dtv = b2f(dtp[0]);
  float xv  = b2f(xsp[0]);
  for (int il = 0; il < 32; ++il) {
    float dtn = 0.f, xn = 0.f;
    if (il < 31) { dtn = b2f(dtp[(il + 1) * 2048]); xn = b2f(xsp[(il + 1) * 2048]); }
    const float dx = dtv * xv;
    sdt += dtv;
    const float* Bv = &Bsh[il * 16];
    #pragma unroll
    for (int s = 0; s < 16; ++s) h[s] = __expf(dtv * Ad[s]) * h[s] + dx * Bv[s];
    dtv = dtn; xv = xn;
  }
  const size_t fo = (((size_t)b * 64 + c) * 2048 + d) * 16;
  #pragma unroll
  for (int q = 0; q < 4; ++q)
    *(float4*)(FH + fo + q * 4) = make_float4(h[q*4], h[q*4+1], h[q*4+2], h[q*4+3]);
  Sdt[((size_t)b * 64 + c) * 2048 + d] = sdt;
}

// Pass B: chunk combine, state-parallel: thread per (b,d,s). In place FH: F -> Hinit.
__global__ __launch_bounds__(256) void scanB_kernel(float* __restrict__ FH,
    const float* __restrict__ Sdt, const float* __restrict__ A_log) {
  const int idx = blockIdx.x * 256 + threadIdx.x;  // 65536 = (b,d,s)
  const int s = idx & 15;
  const int d = (idx >> 4) & 2047;
  const int b = idx >> 15;
  const float Ad = -__expf(A_log[(size_t)d * 16 + s]);
  float H = 0.f;
  #pragma unroll 8
  for (int c = 0; c < 64; ++c) {
    const size_t o = (((size_t)b * 64 + c) * 2048 + d) * 16 + s;
    const float F   = FH[o];
    const float sdt = Sdt[((size_t)b * 64 + c) * 2048 + d];
    FH[o] = H;
    H = __expf(sdt * Ad) * H + F;
  }
}

// Pass C: recompute local scan from initial state; emit gated output. B,C staged in LDS.
__global__ __launch_bounds__(256, 4) void scanC_kernel(const ushort* __restrict__ dt,
    const ushort* __restrict__ xs, const float* __restrict__ xdbl,
    const ushort* __restrict__ xz, const float* __restrict__ A_log,
    const float* __restrict__ Dskip, const float* __restrict__ FH,
    ushort* __restrict__ yg) {
  __shared__ float BCsh[32 * 32];
  const int tid = threadIdx.x;
  const int d = blockIdx.x * 256 + tid;
  const int c = blockIdx.y, b = blockIdx.z;
  const int t0 = b * 2048 + c * 32;
  {
    const int il = tid >> 3, q = (tid & 7) << 2;
    *(float4*)&BCsh[il * 32 + q] = *(const float4*)(xdbl + (size_t)(t0 + il) * 128 + 64 + q);
  }
  float Ad[16];
  #pragma unroll
  for (int s = 0; s < 16; ++s) Ad[s] = -__expf(A_log[(size_t)d * 16 + s]);
  float h[16];
  const size_t ho = (((size_t)b * 64 + c) * 2048 + d) * 16;
  {
    const float4* Hp = (const float4*)(FH + ho);
    float4 H0 = Hp[0], H1 = Hp[1], H2 = Hp[2], H3 = Hp[3];
    h[0]=H0.x; h[1]=H0.y; h[2]=H0.z; h[3]=H0.w;
    h[4]=H1.x; h[5]=H1.y; h[6]=H1.z; h[7]=H1.w;
    h[8]=H2.x; h[9]=H2.y; h[10]=H2.z; h[11]=H2.w;
    h[12]=H3.x; h[13]=H3.y; h[14]=H3.z; h[15]=H3.w;
  }
  __syncthreads();
  const float Dk = Dskip[d];
  const ushort* dtp = dt + (size_t)t0 * 2048 + d;
  const ushort* xsp = xs + (size_t)t0 * 2048 + d;
  const ushort* zp  = xz + (size_t)t0 * 4096 + 2048 + d;
  ushort* ygp = yg + (size_t)t0 * 2048 + d;
  float dtv = b2f(dtp[0]);
  float xv  = b2f(xsp[0]);
  float zv  = b2f(zp[0]);
  for (int il = 0; il < 32; ++il) {
    float dtn = 0.f, xn = 0.f, zn = 0.f;
    if (il < 31) {
      dtn = b2f(dtp[(il + 1) * 2048]);
      xn  = b2f(xsp[(il + 1) * 2048]);
      zn  = b2f(zp[(size_t)(il + 1) * 4096]);
    }
    const float dx = dtv * xv;
    const float* Bv = &BCsh[il * 32];
    const float* Cv = &BCsh[il * 32 + 16];
    float y = 0.f;
    #pragma unroll
    for (int s = 0; s < 16; ++s) {
      h[s] = __expf(dtv * Ad[s]) * h[s] + dx * Bv[s];
      y += h[s] * Cv[s];
    }
    const float g = zv / (1.f + __expf(-zv));
    ygp[il * 2048] = f2b((y + xv * Dk) * g);
    dtv = dtn; xv = xn; zv = zn;
  }
}

// ---------------- launch ----------------
extern "C" void kernel_launch(void* const* d_in, const int* in_sizes, int n_in,
                              void* d_out, int out_size, void* d_ws, size_t ws_size,
                              hipStream_t stream) {
  (void)in_sizes; (void)n_in; (void)out_size; (void)ws_size;
  const float* x       = (const float*)d_in[0];
  const float* ln_w    = (const float*)d_in[1];
  const float* ln_b    = (const float*)d_in[2];
  const float* W_in    = (const float*)d_in[3];
  const float* conv_w  = (const float*)d_in[4];
  const float* conv_b  = (const float*)d_in[5];
  const float* W_xproj = (const float*)d_in[6];
  const float* W_dt    = (const float*)d_in[7];
  const float* b_dt    = (const float*)d_in[8];
  const float* A_log   = (const float*)d_in[9];
  const float* D_skip  = (const float*)d_in[10];
  const float* W_out   = (const float*)d_in[11];
  float* out = (float*)d_out;

  char* ws = (char*)d_ws;
  size_t off = 0;
  auto alloc = [&](size_t bytes) -> void* {
    void* p = ws + off;
    off += (bytes + 255) & ~(size_t)255;
    return p;
  };
  ushort* win_bf   = (ushort*)alloc((size_t)4096 * 1024 * 2);  //  8 MB
  ushort* wout_bf  = (ushort*)alloc((size_t)1024 * 2048 * 2);  //  4 MB
  ushort* wxp_bf   = (ushort*)alloc((size_t)128 * 2048 * 2);   //  0.5 MB
  ushort* wdt_bf   = (ushort*)alloc((size_t)2048 * 64 * 2);    //  0.25 MB
  ushort* xn_bf    = (ushort*)alloc((size_t)4096 * 1024 * 2);  //  8 MB
  ushort* xz_bf    = (ushort*)alloc((size_t)4096 * 4096 * 2);  // 32 MB
  ushort* xs_bf    = (ushort*)alloc((size_t)4096 * 2048 * 2);  // 16 MB
  float*  xdbl     = (float*)alloc((size_t)4096 * 128 * 4);    //  2 MB
  float*  xdbl8    = (float*)alloc((size_t)8 * 4096 * 128 * 4);// 16 MB (aliased: FH after reduce)
  ushort* dtlow_bf = (ushort*)alloc((size_t)4096 * 64 * 2);    //  0.5 MB
  ushort* dtf_bf   = (ushort*)alloc((size_t)4096 * 2048 * 2);  // 16 MB (bf16 dt)
  float*  SdtBuf   = (float*)alloc((size_t)2 * 64 * 2048 * 4); //  1 MB
  ushort* yg_bf    = (ushort*)alloc((size_t)4096 * 2048 * 2);  // 16 MB  (total ~120 MB)
  float*  FH       = xdbl8;  // alias: xdbl8 dead after reduce; FH = 2*64*2048*16 f32 = 16 MB

  prep_weights_kernel<<<6528, 256, 0, stream>>>(W_in, W_out, W_dt, W_xproj,
                                                win_bf, wout_bf, wdt_bf, wxp_bf);
  ln_kernel<<<4096, 256, 0, stream>>>(x, ln_w, ln_b, xn_bf);

  // xz[4096,4096] = xn @ W_in^T   (bf16 out)
  gemm_lds<1><<<dim3(32, 32, 1), 256, 0, stream>>>(xn_bf, win_bf, nullptr, xz_bf, nullptr,
                                                   4096, 4096, 1024, 32);
  conv_silu_kernel<<<8192, 256, 0, stream>>>(xz_bf, conv_w, conv_b, xs_bf);

  // x_dbl slices[8][4096][128] = xs @ Wxp^T  (split-K, non-atomic)
  gemm_lds<2><<<dim3(32, 1, 8), 256, 0, stream>>>(xs_bf, wxp_bf, xdbl8, nullptr, nullptr,
                                                  4096, 128, 2048, 8);
  xdbl_reduce_kernel<<<512, 256, 0, stream>>>(xdbl8, xdbl, dtlow_bf);

  // dt[4096,2048] = softplus(dt_low @ W_dt^T + b_dt)  (bf16 out)
  gemm_lds<3><<<dim3(32, 16, 1), 256, 0, stream>>>(dtlow_bf, wdt_bf, nullptr, dtf_bf, b_dt,
                                                   4096, 2048, 64, 2);

  scanA_kernel<<<dim3(8, 64, 2), 256, 0, stream>>>(dtf_bf, xs_bf, xdbl, A_log, FH, SdtBuf);
  scanB_kernel<<<256, 256, 0, stream>>>(FH, SdtBuf, A_log);
  scanC_kernel<<<dim3(8, 64, 2), 256, 0, stream>>>(dtf_bf, xs_bf, xdbl, xz_bf, A_log, D_skip,
                                                   FH, yg_bf);

  // out[4096,1024] = x + yg @ W_out^T
  gemm_lds<4><<<dim3(32, 8, 1), 256, 0, stream>>>(yg_bf, wout_bf, out, nullptr, x,
                                                  4096, 1024, 2048, 64);
}

// Round 6
// 302.572 us; speedup vs baseline: 1.4383x; 1.0784x over previous
//
#include <hip/hip_runtime.h>
#include <hip/hip_bf16.h>

// Mamba layer: LN -> in_proj GEMM -> conv+SiLU -> xproj GEMM(splitK) -> dt GEMM+softplus
//              -> chunked selective scan (64 chunks, state-parallel combine) -> gate
//              -> out_proj GEMM + residual.
// GEMMs: bf16 MFMA 16x16x32, m97 staging, BM templated (128 wide / 64 skinny),
//        coalesced epilogue via LDS bounce (stride-132 f32, conflict-free).

typedef __attribute__((ext_vector_type(4))) float f32x4;
typedef __attribute__((ext_vector_type(8))) short s16x8;

static __device__ __forceinline__ float b2f(ushort u) {
  union { float f; unsigned int i; } v; v.i = ((unsigned int)u) << 16; return v.f;
}
static __device__ __forceinline__ ushort f2b(float f) {
  union { __hip_bfloat16 h; ushort u; } v; v.h = __float2bfloat16(f); return v.u;
}

#define GLD16(gp, lp) __builtin_amdgcn_global_load_lds( \
    (const __attribute__((address_space(1))) void*)(gp), \
    (__attribute__((address_space(3))) void*)(lp), 16, 0, 0)

// ---------------- merged weight prep (all f32->bf16 casts in one dispatch) ----------
__global__ void prep_weights_kernel(const float* __restrict__ W_in,
    const float* __restrict__ W_out, const float* __restrict__ W_dt,
    const float* __restrict__ W_xproj, ushort* __restrict__ win,
    ushort* __restrict__ wout, ushort* __restrict__ wdt, ushort* __restrict__ wxp) {
  int i = blockIdx.x * 256 + threadIdx.x;     // float4 index
  if (i < 1048576) {
    float4 v = ((const float4*)W_in)[i];
    ((ushort4*)win)[i] = make_ushort4(f2b(v.x), f2b(v.y), f2b(v.z), f2b(v.w));
    return;
  }
  i -= 1048576;
  if (i < 524288) {
    float4 v = ((const float4*)W_out)[i];
    ((ushort4*)wout)[i] = make_ushort4(f2b(v.x), f2b(v.y), f2b(v.z), f2b(v.w));
    return;
  }
  i -= 524288;
  if (i < 32768) {
    float4 v = ((const float4*)W_dt)[i];
    ((ushort4*)wdt)[i] = make_ushort4(f2b(v.x), f2b(v.y), f2b(v.z), f2b(v.w));
    return;
  }
  i -= 32768;
  if (i < 65536) {
    int e  = i >> 9;
    int k4 = (i & 511) << 2;
    ushort4 o = make_ushort4(0, 0, 0, 0);
    if (e < 96) {
      float4 v = *(const float4*)(W_xproj + (size_t)e * 2048 + k4);
      o = make_ushort4(f2b(v.x), f2b(v.y), f2b(v.z), f2b(v.w));
    }
    ((ushort4*)wxp)[i] = o;
  }
}

// ---------------- layernorm -> bf16 ----------------
__global__ __launch_bounds__(256) void ln_kernel(const float* __restrict__ x,
    const float* __restrict__ w, const float* __restrict__ b, ushort* __restrict__ xn) {
  const int row = blockIdx.x;       // 4096 rows of 1024
  const int tid = threadIdx.x;
  float4 v = ((const float4*)(x + (size_t)row * 1024))[tid];
  float s  = v.x + v.y + v.z + v.w;
  float s2 = v.x*v.x + v.y*v.y + v.z*v.z + v.w*v.w;
  #pragma unroll
  for (int off = 32; off; off >>= 1) { s += __shfl_xor(s, off); s2 += __shfl_xor(s2, off); }
  __shared__ float red[8];
  if ((tid & 63) == 0) { red[tid >> 6] = s; red[(tid >> 6) + 4] = s2; }
  __syncthreads();
  float S  = red[0] + red[1] + red[2] + red[3];
  float S2 = red[4] + red[5] + red[6] + red[7];
  float mu   = S * (1.0f / 1024.0f);
  float var  = S2 * (1.0f / 1024.0f) - mu * mu;
  float rstd = rsqrtf(var + 1e-5f);
  float4 wv = ((const float4*)w)[tid];
  float4 bv = ((const float4*)b)[tid];
  ushort4 o = make_ushort4(
      f2b((v.x - mu) * rstd * wv.x + bv.x),
      f2b((v.y - mu) * rstd * wv.y + bv.y),
      f2b((v.z - mu) * rstd * wv.z + bv.z),
      f2b((v.w - mu) * rstd * wv.w + bv.w));
  ((ushort4*)(xn + (size_t)row * 1024))[tid] = o;
}

// ---------------- bf16 MFMA GEMM: C[M,N] = A[M,K] * B[N,K]^T ----------
// BM in {128, 64}; BN = 128. 4 waves as 2x2; wave tile (BM/2) x 64.
// EPI: 1 = store bf16, 2 = store fp32 slice (split-K, slice = blockIdx.z),
//      3 = +bias[col], softplus, store bf16, 4 = residual: Cf[o] = aux[o] + v
template<int EPI, int BM>
__global__ __launch_bounds__(256, 2) void gemm_lds(
    const ushort* __restrict__ A, const ushort* __restrict__ B,
    float* __restrict__ Cf, ushort* __restrict__ Cb,
    const float* __restrict__ aux,
    int M, int N, int K, int kt_per)
{
  constexpr int MF  = BM / 32;             // m-frags per wave (4 or 2)
  constexpr int RSH = (BM == 128) ? 6 : 5; // wave row-band shift in epilogue
  __shared__ __align__(16) char SM[16896]; // staging (<=16K) / epi 32x132 f32 (16896)
  ushort* As = (ushort*)SM;
  ushort* Bs = (ushort*)(SM + BM * 64);    // A region = BM rows * 64 B
  float*  epi = (float*)SM;
  const int tid  = threadIdx.x;
  const int lane = tid & 63;
  const int wid  = tid >> 6;
  const int wr = wid >> 1, wc = wid & 1;
  const int m0 = blockIdx.x * BM, n0 = blockIdx.y * 128;
  const int kt0 = blockIdx.z * kt_per;

  const int srow = tid >> 2;            // 0..63
  const int scol = (tid & 3) << 3;      // 0,8,16,24 (elements)
  const ushort* Ag0 = A + (size_t)(m0 + srow) * K + scol + (size_t)kt0 * 32;
  const ushort* Ag1 = Ag0 + (size_t)64 * K;
  const ushort* Bg0 = B + (size_t)(n0 + srow) * K + scol + (size_t)kt0 * 32;
  const ushort* Bg1 = Bg0 + (size_t)64 * K;
  char* ldsA0 = (char*)As + wid * 1024;          // wave-uniform bases
  char* ldsA1 = (char*)As + 4096 + wid * 1024;   // only for BM==128
  char* ldsB0 = (char*)Bs + wid * 1024;
  char* ldsB1 = (char*)Bs + 4096 + wid * 1024;

  f32x4 acc[MF][4];
  #pragma unroll
  for (int m = 0; m < MF; ++m)
    #pragma unroll
    for (int n = 0; n < 4; ++n)
      acc[m][n] = (f32x4){0.f, 0.f, 0.f, 0.f};

  const int frow = lane & 15;
  const int fk   = (lane >> 4) << 3;
  const ushort* AsR = As + (wr * (BM / 2) + frow) * 32 + fk;
  const ushort* BsR = Bs + (wc * 64 + frow) * 32 + fk;

  for (int kt = 0; kt < kt_per; ++kt) {
    const size_t ko = (size_t)kt * 32;
    GLD16(Ag0 + ko, ldsA0);
    if constexpr (BM == 128) GLD16(Ag1 + ko, ldsA1);
    GLD16(Bg0 + ko, ldsB0);
    GLD16(Bg1 + ko, ldsB1);
    __syncthreads();
    s16x8 af[MF], bfr[4];
    #pragma unroll
    for (int m = 0; m < MF; ++m) af[m] = *(const s16x8*)(AsR + m * 512);
    #pragma unroll
    for (int n = 0; n < 4; ++n) bfr[n] = *(const s16x8*)(BsR + n * 512);
    #pragma unroll
    for (int m = 0; m < MF; ++m)
      #pragma unroll
      for (int n = 0; n < 4; ++n)
        acc[m][n] = __builtin_amdgcn_mfma_f32_16x16x32_bf16(af[m], bfr[n], acc[m][n], 0, 0, 0);
    __syncthreads();
  }

  // ---- coalesced epilogue: MF phases of 32 rows through LDS (stride 132) ----
  const int rl = tid >> 3;              // 0..31  (band row)
  const int c0 = (tid & 7) << 4;        // 0,16,...,112
  const size_t zoff = (EPI == 2) ? (size_t)blockIdx.z * M * N : 0;
  #pragma unroll
  for (int m = 0; m < MF; ++m) {
    #pragma unroll
    for (int n = 0; n < 4; ++n) {
      const int cl = wc * 64 + n * 16 + (lane & 15);
      #pragma unroll
      for (int j = 0; j < 4; ++j) {
        const int rr = wr * 16 + ((lane >> 4) << 2) + j;
        epi[rr * 132 + cl] = acc[m][n][j];
      }
    }
    __syncthreads();
    const int grow = m0 + ((rl >> 4) << RSH) + m * 16 + (rl & 15);
    const int gcol = n0 + c0;
    float v[16];
    #pragma unroll
    for (int q = 0; q < 16; ++q) v[q] = epi[rl * 132 + c0 + q];
    if (EPI == 1) {
      ushort u[16];
      #pragma unroll
      for (int q = 0; q < 16; ++q) u[q] = f2b(v[q]);
      *(int4*)(Cb + (size_t)grow * N + gcol)     = *(int4*)&u[0];
      *(int4*)(Cb + (size_t)grow * N + gcol + 8) = *(int4*)&u[8];
    } else if (EPI == 2) {
      #pragma unroll
      for (int q = 0; q < 4; ++q)
        *(float4*)(Cf + zoff + (size_t)grow * N + gcol + q * 4) = *(float4*)&v[q * 4];
    } else if (EPI == 3) {
      ushort u[16];
      #pragma unroll
      for (int q = 0; q < 4; ++q) {
        float4 bb = *(const float4*)(aux + gcol + q * 4);
        float t0 = v[q*4+0] + bb.x, t1 = v[q*4+1] + bb.y;
        float t2 = v[q*4+2] + bb.z, t3 = v[q*4+3] + bb.w;
        u[q*4+0] = f2b(fmaxf(t0, 0.f) + __logf(1.f + __expf(-fabsf(t0))));
        u[q*4+1] = f2b(fmaxf(t1, 0.f) + __logf(1.f + __expf(-fabsf(t1))));
        u[q*4+2] = f2b(fmaxf(t2, 0.f) + __logf(1.f + __expf(-fabsf(t2))));
        u[q*4+3] = f2b(fmaxf(t3, 0.f) + __logf(1.f + __expf(-fabsf(t3))));
      }
      *(int4*)(Cb + (size_t)grow * N + gcol)     = *(int4*)&u[0];
      *(int4*)(Cb + (size_t)grow * N + gcol + 8) = *(int4*)&u[8];
    } else {
      #pragma unroll
      for (int q = 0; q < 4; ++q) {
        float4 rr2 = *(const float4*)(aux + (size_t)grow * N + gcol + q * 4);
        float4 ov = make_float4(rr2.x + v[q*4+0], rr2.y + v[q*4+1],
                                rr2.z + v[q*4+2], rr2.w + v[q*4+3]);
        *(float4*)(Cf + (size_t)grow * N + gcol + q * 4) = ov;
      }
    }
    __syncthreads();
  }
}

// ---------------- depthwise causal conv1d + SiLU (4 ch x 4 l per thread) ----------
__global__ __launch_bounds__(256) void conv_silu_kernel(const ushort* __restrict__ xz,
    const float* __restrict__ cw, const float* __restrict__ cb, ushort* __restrict__ xs) {
  const int idx = blockIdx.x * 256 + threadIdx.x;  // 524288 = 2 * 512lg * 512d4
  const int d4 = idx & 511;
  const int lg = (idx >> 9) & 511;
  const int b  = idx >> 18;
  const int d  = d4 << 2;
  const int l0 = lg << 2;
  float w[4][4];
  const float* cwd = cw + d * 4;
  #pragma unroll
  for (int j = 0; j < 4; ++j)
    #pragma unroll
    for (int t = 0; t < 4; ++t) w[j][t] = cwd[j * 4 + t];
  const float4 bias = *(const float4*)(cb + d);
  float vin[7][4];
  const size_t base = (size_t)(b * 2048) * 4096 + d;
  #pragma unroll
  for (int j = 0; j < 7; ++j) {
    const int ls = l0 - 3 + j;
    if (ls >= 0) {
      ushort4 xv = *(const ushort4*)(xz + base + (size_t)ls * 4096);
      vin[j][0] = b2f(xv.x); vin[j][1] = b2f(xv.y);
      vin[j][2] = b2f(xv.z); vin[j][3] = b2f(xv.w);
    } else {
      vin[j][0] = vin[j][1] = vin[j][2] = vin[j][3] = 0.f;
    }
  }
  #pragma unroll
  for (int i = 0; i < 4; ++i) {
    float a0 = bias.x, a1 = bias.y, a2 = bias.z, a3 = bias.w;
    #pragma unroll
    for (int t = 0; t < 4; ++t) {
      a0 += vin[i + t][0] * w[0][t];
      a1 += vin[i + t][1] * w[1][t];
      a2 += vin[i + t][2] * w[2][t];
      a3 += vin[i + t][3] * w[3][t];
    }
    ushort4 o;
    o.x = f2b(a0 / (1.f + __expf(-a0)));
    o.y = f2b(a1 / (1.f + __expf(-a1)));
    o.z = f2b(a2 / (1.f + __expf(-a2)));
    o.w = f2b(a3 / (1.f + __expf(-a3)));
    *(ushort4*)(xs + (size_t)(b * 2048 + l0 + i) * 2048 + d) = o;
  }
}

// ---------------- xproj split-K reduce + dtlow cast ----------------
__global__ __launch_bounds__(256) void xdbl_reduce_kernel(const float* __restrict__ x8,
    float* __restrict__ xdbl, ushort* __restrict__ dtlow) {
  const int i = blockIdx.x * 256 + threadIdx.x;  // 131072 = 4096*128/4
  const int r = i >> 5, c4 = (i & 31) << 2;
  float4 s = make_float4(0.f, 0.f, 0.f, 0.f);
  #pragma unroll
  for (int z = 0; z < 8; ++z) {
    float4 v = *(const float4*)(x8 + (size_t)z * 524288 + (size_t)r * 128 + c4);
    s.x += v.x; s.y += v.y; s.z += v.z; s.w += v.w;
  }
  *(float4*)(xdbl + (size_t)r * 128 + c4) = s;
  if (c4 < 64) {
    ((ushort4*)(dtlow + (size_t)r * 64))[c4 >> 2] =
        make_ushort4(f2b(s.x), f2b(s.y), f2b(s.z), f2b(s.w));
  }
}

// ---------------- chunked selective scan: 64 chunks of 32 ----------------
// Pass A: local scan h0=0, store final state + sum(dt). B staged in LDS.
__global__ __launch_bounds__(256, 4) void scanA_kernel(const ushort* __restrict__ dt,
    const ushort* __restrict__ xs, const float* __restrict__ xdbl,
    const float* __restrict__ A_log, float* __restrict__ FH, float* __restrict__ Sdt) {
  __shared__ float Bsh[32 * 16];
  const int tid = threadIdx.x;
  const int d = blockIdx.x * 256 + tid;
  const int c = blockIdx.y, b = blockIdx.z;
  const int t0 = b * 2048 + c * 32;
  if (tid < 128) {
    const int il = tid >> 2, q = (tid & 3) << 2;
    *(float4*)&Bsh[il * 16 + q] = *(const float4*)(xdbl + (size_t)(t0 + il) * 128 + 64 + q);
  }
  float Ad[16];
  #pragma unroll
  for (int s = 0; s < 16; ++s) Ad[s] = -__expf(A_log[(size_t)d * 16 + s]);
  __syncthreads();
  float h[16];
  #pragma unroll
  for (int s = 0; s < 16; ++s) h[s] = 0.f;
  float sdt = 0.f;
  const ushort* dtp = dt + (size_t)t0 * 2048 + d;
  const ushort* xsp = xs + (size_t)t0 * 2048 + d;
  float dtv = b2f(dtp[0]);
  float xv  = b2f(xsp[0]);
  for (int il = 0; il < 32; ++il) {
    float dtn = 0.f, xn = 0.f;
    if (il < 31) { dtn = b2f(dtp[(il + 1) * 2048]); xn = b2f(xsp[(il + 1) * 2048]); }
    const float dx = dtv * xv;
    sdt += dtv;
    const float* Bv = &Bsh[il * 16];
    #pragma unroll
    for (int s = 0; s < 16; ++s) h[s] = __expf(dtv * Ad[s]) * h[s] + dx * Bv[s];
    dtv = dtn; xv = xn;
  }
  const size_t fo = (((size_t)b * 64 + c) * 2048 + d) * 16;
  #pragma unroll
  for (int q = 0; q < 4; ++q)
    *(float4*)(FH + fo + q * 4) = make_float4(h[q*4], h[q*4+1], h[q*4+2], h[q*4+3]);
  Sdt[((size_t)b * 64 + c) * 2048 + d] = sdt;
}

// Pass B: chunk combine, state-parallel: thread per (b,d,s). In place FH: F -> Hinit.
__global__ __launch_bounds__(256) void scanB_kernel(float* __restrict__ FH,
    const float* __restrict__ Sdt, const float* __restrict__ A_log) {
  const int idx = blockIdx.x * 256 + threadIdx.x;  // 65536 = (b,d,s)
  const int s = idx & 15;
  const int d = (idx >> 4) & 2047;
  const int b = idx >> 15;
  const float Ad = -__expf(A_log[(size_t)d * 16 + s]);
  float H = 0.f;
  #pragma unroll 8
  for (int c = 0; c < 64; ++c) {
    const size_t o = (((size_t)b * 64 + c) * 2048 + d) * 16 + s;
    const float F   = FH[o];
    const float sdt = Sdt[((size_t)b * 64 + c) * 2048 + d];
    FH[o] = H;
    H = __expf(sdt * Ad) * H + F;
  }
}

// Pass C: recompute local scan from initial state; emit gated output. B,C staged in LDS.
__global__ __launch_bounds__(256, 4) void scanC_kernel(const ushort* __restrict__ dt,
    const ushort* __restrict__ xs, const float* __restrict__ xdbl,
    const ushort* __restrict__ xz, const float* __restrict__ A_log,
    const float* __restrict__ Dskip, const float* __restrict__ FH,
    ushort* __restrict__ yg) {
  __shared__ float BCsh[32 * 32];
  const int tid = threadIdx.x;
  const int d = blockIdx.x * 256 + tid;
  const int c = blockIdx.y, b = blockIdx.z;
  const int t0 = b * 2048 + c * 32;
  {
    const int il = tid >> 3, q = (tid & 7) << 2;
    *(float4*)&BCsh[il * 32 + q] = *(const float4*)(xdbl + (size_t)(t0 + il) * 128 + 64 + q);
  }
  float Ad[16];
  #pragma unroll
  for (int s = 0; s < 16; ++s) Ad[s] = -__expf(A_log[(size_t)d * 16 + s]);
  float h[16];
  const size_t ho = (((size_t)b * 64 + c) * 2048 + d) * 16;
  {
    const float4* Hp = (const float4*)(FH + ho);
    float4 H0 = Hp[0], H1 = Hp[1], H2 = Hp[2], H3 = Hp[3];
    h[0]=H0.x; h[1]=H0.y; h[2]=H0.z; h[3]=H0.w;
    h[4]=H1.x; h[5]=H1.y; h[6]=H1.z; h[7]=H1.w;
    h[8]=H2.x; h[9]=H2.y; h[10]=H2.z; h[11]=H2.w;
    h[12]=H3.x; h[13]=H3.y; h[14]=H3.z; h[15]=H3.w;
  }
  __syncthreads();
  const float Dk = Dskip[d];
  const ushort* dtp = dt + (size_t)t0 * 2048 + d;
  const ushort* xsp = xs + (size_t)t0 * 2048 + d;
  const ushort* zp  = xz + (size_t)t0 * 4096 + 2048 + d;
  ushort* ygp = yg + (size_t)t0 * 2048 + d;
  float dtv = b2f(dtp[0]);
  float xv  = b2f(xsp[0]);
  float zv  = b2f(zp[0]);
  for (int il = 0; il < 32; ++il) {
    float dtn = 0.f, xn = 0.f, zn = 0.f;
    if (il < 31) {
      dtn = b2f(dtp[(il + 1) * 2048]);
      xn  = b2f(xsp[(il + 1) * 2048]);
      zn  = b2f(zp[(size_t)(il + 1) * 4096]);
    }
    const float dx = dtv * xv;
    const float* Bv = &BCsh[il * 32];
    const float* Cv = &BCsh[il * 32 + 16];
    float y = 0.f;
    #pragma unroll
    for (int s = 0; s < 16; ++s) {
      h[s] = __expf(dtv * Ad[s]) * h[s] + dx * Bv[s];
      y += h[s] * Cv[s];
    }
    const float g = zv / (1.f + __expf(-zv));
    ygp[il * 2048] = f2b((y + xv * Dk) * g);
    dtv = dtn; xv = xn; zv = zn;
  }
}

// ---------------- launch ----------------
extern "C" void kernel_launch(void* const* d_in, const int* in_sizes, int n_in,
                              void* d_out, int out_size, void* d_ws, size_t ws_size,
                              hipStream_t stream) {
  (void)in_sizes; (void)n_in; (void)out_size; (void)ws_size;
  const float* x       = (const float*)d_in[0];
  const float* ln_w    = (const float*)d_in[1];
  const float* ln_b    = (const float*)d_in[2];
  const float* W_in    = (const float*)d_in[3];
  const float* conv_w  = (const float*)d_in[4];
  const float* conv_b  = (const float*)d_in[5];
  const float* W_xproj = (const float*)d_in[6];
  const float* W_dt    = (const float*)d_in[7];
  const float* b_dt    = (const float*)d_in[8];
  const float* A_log   = (const float*)d_in[9];
  const float* D_skip  = (const float*)d_in[10];
  const float* W_out   = (const float*)d_in[11];
  float* out = (float*)d_out;

  char* ws = (char*)d_ws;
  size_t off = 0;
  auto alloc = [&](size_t bytes) -> void* {
    void* p = ws + off;
    off += (bytes + 255) & ~(size_t)255;
    return p;
  };
  ushort* win_bf   = (ushort*)alloc((size_t)4096 * 1024 * 2);  //  8 MB
  ushort* wout_bf  = (ushort*)alloc((size_t)1024 * 2048 * 2);  //  4 MB
  ushort* wxp_bf   = (ushort*)alloc((size_t)128 * 2048 * 2);   //  0.5 MB
  ushort* wdt_bf   = (ushort*)alloc((size_t)2048 * 64 * 2);    //  0.25 MB
  ushort* xn_bf    = (ushort*)alloc((size_t)4096 * 1024 * 2);  //  8 MB
  ushort* xz_bf    = (ushort*)alloc((size_t)4096 * 4096 * 2);  // 32 MB
  ushort* xs_bf    = (ushort*)alloc((size_t)4096 * 2048 * 2);  // 16 MB
  float*  xdbl     = (float*)alloc((size_t)4096 * 128 * 4);    //  2 MB
  float*  xdbl8    = (float*)alloc((size_t)8 * 4096 * 128 * 4);// 16 MB (aliased: FH after reduce)
  ushort* dtlow_bf = (ushort*)alloc((size_t)4096 * 64 * 2);    //  0.5 MB
  ushort* dtf_bf   = (ushort*)alloc((size_t)4096 * 2048 * 2);  // 16 MB (bf16 dt)
  float*  SdtBuf   = (float*)alloc((size_t)2 * 64 * 2048 * 4); //  1 MB
  ushort* yg_bf    = (ushort*)alloc((size_t)4096 * 2048 * 2);  // 16 MB  (total ~120 MB)
  float*  FH       = xdbl8;  // alias: xdbl8 dead after reduce; FH = 2*64*2048*16 f32 = 16 MB

  prep_weights_kernel<<<6528, 256, 0, stream>>>(W_in, W_out, W_dt, W_xproj,
                                                win_bf, wout_bf, wdt_bf, wxp_bf);
  ln_kernel<<<4096, 256, 0, stream>>>(x, ln_w, ln_b, xn_bf);

  // xz[4096,4096] = xn @ W_in^T   (bf16 out)
  gemm_lds<1, 128><<<dim3(32, 32, 1), 256, 0, stream>>>(xn_bf, win_bf, nullptr, xz_bf,
                                                        nullptr, 4096, 4096, 1024, 32);
  conv_silu_kernel<<<2048, 256, 0, stream>>>(xz_bf, conv_w, conv_b, xs_bf);

  // x_dbl slices[8][4096][128] = xs @ Wxp^T  (split-K, non-atomic)
  gemm_lds<2, 64><<<dim3(64, 1, 8), 256, 0, stream>>>(xs_bf, wxp_bf, xdbl8, nullptr,
                                                      nullptr, 4096, 128, 2048, 8);
  xdbl_reduce_kernel<<<512, 256, 0, stream>>>(xdbl8, xdbl, dtlow_bf);

  // dt[4096,2048] = softplus(dt_low @ W_dt^T + b_dt)  (bf16 out)
  gemm_lds<3, 64><<<dim3(64, 16, 1), 256, 0, stream>>>(dtlow_bf, wdt_bf, nullptr, dtf_bf,
                                                       b_dt, 4096, 2048, 64, 2);

  scanA_kernel<<<dim3(8, 64, 2), 256, 0, stream>>>(dtf_bf, xs_bf, xdbl, A_log, FH, SdtBuf);
  scanB_kernel<<<256, 256, 0, stream>>>(FH, SdtBuf, A_log);
  scanC_kernel<<<dim3(8, 64, 2), 256, 0, stream>>>(dtf_bf, xs_bf, xdbl, xz_bf, A_log, D_skip,
                                                   FH, yg_bf);

  // out[4096,1024] = x + yg @ W_out^T
  gemm_lds<4, 64><<<dim3(64, 8, 1), 256, 0, stream>>>(yg_bf, wout_bf, out, nullptr, x,
                                                      4096, 1024, 2048, 64);
}

// Round 7
// 290.717 us; speedup vs baseline: 1.4969x; 1.0408x over previous
//
#include <hip/hip_runtime.h>
#include <hip/hip_bf16.h>

// Mamba layer: LN -> in_proj GEMM -> conv+SiLU -> xproj GEMM(splitK) -> dt GEMM+softplus
//              -> chunked selective scan (64 chunks, state-parallel combine) -> gate
//              -> out_proj GEMM + residual.
// GEMM: bf16 MFMA 16x16x32, BM=64/BN=128/BK=64, double-buffered LDS (STAGE(t+1)
//       issued before COMPUTE(t), one barrier/tile), XOR-swizzled staging
//       (LDS[r][c] = A[r][c ^ ((r&7)<<3)], applied on global source + frag read),
//       coalesced epilogue via LDS bounce (stride-132 f32).

typedef __attribute__((ext_vector_type(4))) float f32x4;
typedef __attribute__((ext_vector_type(8))) short s16x8;

static __device__ __forceinline__ float b2f(ushort u) {
  union { float f; unsigned int i; } v; v.i = ((unsigned int)u) << 16; return v.f;
}
static __device__ __forceinline__ ushort f2b(float f) {
  union { __hip_bfloat16 h; ushort u; } v; v.h = __float2bfloat16(f); return v.u;
}

#define GLD16(gp, lp) __builtin_amdgcn_global_load_lds( \
    (const __attribute__((address_space(1))) void*)(gp), \
    (__attribute__((address_space(3))) void*)(lp), 16, 0, 0)

// ---------------- merged weight prep (all f32->bf16 casts in one dispatch) ----------
__global__ void prep_weights_kernel(const float* __restrict__ W_in,
    const float* __restrict__ W_out, const float* __restrict__ W_dt,
    const float* __restrict__ W_xproj, ushort* __restrict__ win,
    ushort* __restrict__ wout, ushort* __restrict__ wdt, ushort* __restrict__ wxp) {
  int i = blockIdx.x * 256 + threadIdx.x;     // float4 index
  if (i < 1048576) {
    float4 v = ((const float4*)W_in)[i];
    ((ushort4*)win)[i] = make_ushort4(f2b(v.x), f2b(v.y), f2b(v.z), f2b(v.w));
    return;
  }
  i -= 1048576;
  if (i < 524288) {
    float4 v = ((const float4*)W_out)[i];
    ((ushort4*)wout)[i] = make_ushort4(f2b(v.x), f2b(v.y), f2b(v.z), f2b(v.w));
    return;
  }
  i -= 524288;
  if (i < 32768) {
    float4 v = ((const float4*)W_dt)[i];
    ((ushort4*)wdt)[i] = make_ushort4(f2b(v.x), f2b(v.y), f2b(v.z), f2b(v.w));
    return;
  }
  i -= 32768;
  if (i < 65536) {
    int e  = i >> 9;
    int k4 = (i & 511) << 2;
    ushort4 o = make_ushort4(0, 0, 0, 0);
    if (e < 96) {
      float4 v = *(const float4*)(W_xproj + (size_t)e * 2048 + k4);
      o = make_ushort4(f2b(v.x), f2b(v.y), f2b(v.z), f2b(v.w));
    }
    ((ushort4*)wxp)[i] = o;
  }
}

// ---------------- layernorm -> bf16 ----------------
__global__ __launch_bounds__(256) void ln_kernel(const float* __restrict__ x,
    const float* __restrict__ w, const float* __restrict__ b, ushort* __restrict__ xn) {
  const int row = blockIdx.x;       // 4096 rows of 1024
  const int tid = threadIdx.x;
  float4 v = ((const float4*)(x + (size_t)row * 1024))[tid];
  float s  = v.x + v.y + v.z + v.w;
  float s2 = v.x*v.x + v.y*v.y + v.z*v.z + v.w*v.w;
  #pragma unroll
  for (int off = 32; off; off >>= 1) { s += __shfl_xor(s, off); s2 += __shfl_xor(s2, off); }
  __shared__ float red[8];
  if ((tid & 63) == 0) { red[tid >> 6] = s; red[(tid >> 6) + 4] = s2; }
  __syncthreads();
  float S  = red[0] + red[1] + red[2] + red[3];
  float S2 = red[4] + red[5] + red[6] + red[7];
  float mu   = S * (1.0f / 1024.0f);
  float var  = S2 * (1.0f / 1024.0f) - mu * mu;
  float rstd = rsqrtf(var + 1e-5f);
  float4 wv = ((const float4*)w)[tid];
  float4 bv = ((const float4*)b)[tid];
  ushort4 o = make_ushort4(
      f2b((v.x - mu) * rstd * wv.x + bv.x),
      f2b((v.y - mu) * rstd * wv.y + bv.y),
      f2b((v.z - mu) * rstd * wv.z + bv.z),
      f2b((v.w - mu) * rstd * wv.w + bv.w));
  ((ushort4*)(xn + (size_t)row * 1024))[tid] = o;
}

// ---------------- bf16 MFMA GEMM: C[M,N] = A[M,K] * B[N,K]^T ----------
// BM=64, BN=128, BK=64. 4 waves 2x2; wave tile 32x64. Double-buffered LDS.
// EPI: 1 = store bf16, 2 = store fp32 slice (split-K, slice = blockIdx.z),
//      3 = +bias[col], softplus, store bf16, 4 = residual: Cf[o] = aux[o] + v
template<int EPI>
__global__ __launch_bounds__(256, 2) void gemm_db(
    const ushort* __restrict__ A, const ushort* __restrict__ B,
    float* __restrict__ Cf, ushort* __restrict__ Cb,
    const float* __restrict__ aux,
    int M, int N, int K, int kt_per)
{
  // buffer: A 64x64 bf16 (8KB) + B 128x64 (16KB) = 24KB; x2 dbuf = 48KB.
  // epilogue reuses SM as 32x132 f32 (16.9KB).
  __shared__ __align__(16) char SM[49152];
  const int tid  = threadIdx.x;
  const int lane = tid & 63;
  const int wid  = tid >> 6;
  const int wr = wid >> 1, wc = wid & 1;
  const int m0 = blockIdx.x * 64, n0 = blockIdx.y * 128;
  const int kt0 = blockIdx.z * kt_per;

  // staging: round covers 32 rows; lane l -> row (l>>3), slot (l&7)*16B.
  // swizzled source col: ((tid&7) ^ (srow&7)) * 8 elements.
  const int srow = tid >> 3;                       // 0..31
  const int sxor = ((tid & 7) ^ (srow & 7)) << 3;  // element offset in row
  const ushort* Ag = A + (size_t)(m0 + srow) * K + sxor + (size_t)kt0 * 64;
  const ushort* Bg = B + (size_t)(n0 + srow) * K + sxor + (size_t)kt0 * 64;
  const size_t rstep = (size_t)32 * K;             // 32 rows per GLD round
  char* lds0 = (char*)SM + wid * 1024;             // wave-uniform base

  f32x4 acc[2][4];
  #pragma unroll
  for (int m = 0; m < 2; ++m)
    #pragma unroll
    for (int n = 0; n < 4; ++n)
      acc[m][n] = (f32x4){0.f, 0.f, 0.f, 0.f};

  const int frow = lane & 15;
  const int fk   = (lane >> 4) << 3;   // 0,8,16,24
  const int sw   = (lane & 7) << 3;    // read-side swizzle (row&7 == frow&7 == lane&7)

#define STAGE(sel, ktv) { \
    const ushort* ag = Ag + (size_t)(ktv) * 64; \
    const ushort* bg = Bg + (size_t)(ktv) * 64; \
    char* ba = lds0 + (sel) * 24576; \
    GLD16(ag,             ba); \
    GLD16(ag + rstep,     ba + 4096); \
    GLD16(bg,             ba + 8192); \
    GLD16(bg + rstep,     ba + 12288); \
    GLD16(bg + 2 * rstep, ba + 16384); \
    GLD16(bg + 3 * rstep, ba + 20480); \
  }

#define COMPUTE(sel) { \
    const ushort* Asb = (const ushort*)((const char*)SM + (sel) * 24576); \
    const ushort* Bsb = Asb + 4096; /* 8192 bytes */ \
    _Pragma("unroll") \
    for (int kk = 0; kk < 2; ++kk) { \
      const int col = (kk * 32 + fk) ^ sw; \
      s16x8 af[2], bf[4]; \
      _Pragma("unroll") \
      for (int m = 0; m < 2; ++m) \
        af[m] = *(const s16x8*)(Asb + (wr * 32 + m * 16 + frow) * 64 + col); \
      _Pragma("unroll") \
      for (int n = 0; n < 4; ++n) \
        bf[n] = *(const s16x8*)(Bsb + (wc * 64 + n * 16 + frow) * 64 + col); \
      _Pragma("unroll") \
      for (int m = 0; m < 2; ++m) \
        _Pragma("unroll") \
        for (int n = 0; n < 4; ++n) \
          acc[m][n] = __builtin_amdgcn_mfma_f32_16x16x32_bf16(af[m], bf[n], acc[m][n], 0, 0, 0); \
    } \
  }

  STAGE(0, 0);
  __syncthreads();
  int c = 0;
  for (int kt = 0; kt < kt_per - 1; ++kt) {
    STAGE(c ^ 1, kt + 1);   // loads for t+1 fly under compute of t
    COMPUTE(c);
    __syncthreads();        // drains vmcnt/lgkm AFTER compute: latency hidden
    c ^= 1;
  }
  COMPUTE(c);
  __syncthreads();          // LDS reuse for epilogue

  // ---- coalesced epilogue: 2 phases of 32 rows through LDS (stride 132) ----
  float* epi = (float*)SM;
  const int rl = tid >> 3;              // 0..31
  const int c0 = (tid & 7) << 4;        // 0,16,...,112
  const size_t zoff = (EPI == 2) ? (size_t)blockIdx.z * M * N : 0;
  #pragma unroll
  for (int m = 0; m < 2; ++m) {
    #pragma unroll
    for (int n = 0; n < 4; ++n) {
      const int cl = wc * 64 + n * 16 + (lane & 15);
      #pragma unroll
      for (int j = 0; j < 4; ++j) {
        const int rr = wr * 16 + ((lane >> 4) << 2) + j;
        epi[rr * 132 + cl] = acc[m][n][j];
      }
    }
    __syncthreads();
    const int grow = m0 + ((rl >> 4) << 5) + m * 16 + (rl & 15);
    const int gcol = n0 + c0;
    float v[16];
    #pragma unroll
    for (int q = 0; q < 16; ++q) v[q] = epi[rl * 132 + c0 + q];
    if (EPI == 1) {
      ushort u[16];
      #pragma unroll
      for (int q = 0; q < 16; ++q) u[q] = f2b(v[q]);
      *(int4*)(Cb + (size_t)grow * N + gcol)     = *(int4*)&u[0];
      *(int4*)(Cb + (size_t)grow * N + gcol + 8) = *(int4*)&u[8];
    } else if (EPI == 2) {
      #pragma unroll
      for (int q = 0; q < 4; ++q)
        *(float4*)(Cf + zoff + (size_t)grow * N + gcol + q * 4) = *(float4*)&v[q * 4];
    } else if (EPI == 3) {
      ushort u[16];
      #pragma unroll
      for (int q = 0; q < 4; ++q) {
        float4 bb = *(const float4*)(aux + gcol + q * 4);
        float t0 = v[q*4+0] + bb.x, t1 = v[q*4+1] + bb.y;
        float t2 = v[q*4+2] + bb.z, t3 = v[q*4+3] + bb.w;
        u[q*4+0] = f2b(fmaxf(t0, 0.f) + __logf(1.f + __expf(-fabsf(t0))));
        u[q*4+1] = f2b(fmaxf(t1, 0.f) + __logf(1.f + __expf(-fabsf(t1))));
        u[q*4+2] = f2b(fmaxf(t2, 0.f) + __logf(1.f + __expf(-fabsf(t2))));
        u[q*4+3] = f2b(fmaxf(t3, 0.f) + __logf(1.f + __expf(-fabsf(t3))));
      }
      *(int4*)(Cb + (size_t)grow * N + gcol)     = *(int4*)&u[0];
      *(int4*)(Cb + (size_t)grow * N + gcol + 8) = *(int4*)&u[8];
    } else {
      #pragma unroll
      for (int q = 0; q < 4; ++q) {
        float4 rr2 = *(const float4*)(aux + (size_t)grow * N + gcol + q * 4);
        float4 ov = make_float4(rr2.x + v[q*4+0], rr2.y + v[q*4+1],
                                rr2.z + v[q*4+2], rr2.w + v[q*4+3]);
        *(float4*)(Cf + (size_t)grow * N + gcol + q * 4) = ov;
      }
    }
    __syncthreads();
  }
#undef STAGE
#undef COMPUTE
}

// ---------------- depthwise causal conv1d + SiLU (4 ch x 4 l per thread) ----------
__global__ __launch_bounds__(256) void conv_silu_kernel(const ushort* __restrict__ xz,
    const float* __restrict__ cw, const float* __restrict__ cb, ushort* __restrict__ xs) {
  const int idx = blockIdx.x * 256 + threadIdx.x;  // 524288 = 2 * 512lg * 512d4
  const int d4 = idx & 511;
  const int lg = (idx >> 9) & 511;
  const int b  = idx >> 18;
  const int d  = d4 << 2;
  const int l0 = lg << 2;
  float w[4][4];
  const float* cwd = cw + d * 4;
  #pragma unroll
  for (int j = 0; j < 4; ++j)
    #pragma unroll
    for (int t = 0; t < 4; ++t) w[j][t] = cwd[j * 4 + t];
  const float4 bias = *(const float4*)(cb + d);
  float vin[7][4];
  const size_t base = (size_t)(b * 2048) * 4096 + d;
  #pragma unroll
  for (int j = 0; j < 7; ++j) {
    const int ls = l0 - 3 + j;
    if (ls >= 0) {
      ushort4 xv = *(const ushort4*)(xz + base + (size_t)ls * 4096);
      vin[j][0] = b2f(xv.x); vin[j][1] = b2f(xv.y);
      vin[j][2] = b2f(xv.z); vin[j][3] = b2f(xv.w);
    } else {
      vin[j][0] = vin[j][1] = vin[j][2] = vin[j][3] = 0.f;
    }
  }
  #pragma unroll
  for (int i = 0; i < 4; ++i) {
    float a0 = bias.x, a1 = bias.y, a2 = bias.z, a3 = bias.w;
    #pragma unroll
    for (int t = 0; t < 4; ++t) {
      a0 += vin[i + t][0] * w[0][t];
      a1 += vin[i + t][1] * w[1][t];
      a2 += vin[i + t][2] * w[2][t];
      a3 += vin[i + t][3] * w[3][t];
    }
    ushort4 o;
    o.x = f2b(a0 / (1.f + __expf(-a0)));
    o.y = f2b(a1 / (1.f + __expf(-a1)));
    o.z = f2b(a2 / (1.f + __expf(-a2)));
    o.w = f2b(a3 / (1.f + __expf(-a3)));
    *(ushort4*)(xs + (size_t)(b * 2048 + l0 + i) * 2048 + d) = o;
  }
}

// ---------------- xproj split-K reduce + dtlow cast ----------------
__global__ __launch_bounds__(256) void xdbl_reduce_kernel(const float* __restrict__ x8,
    float* __restrict__ xdbl, ushort* __restrict__ dtlow) {
  const int i = blockIdx.x * 256 + threadIdx.x;  // 131072 = 4096*128/4
  const int r = i >> 5, c4 = (i & 31) << 2;
  float4 s = make_float4(0.f, 0.f, 0.f, 0.f);
  #pragma unroll
  for (int z = 0; z < 8; ++z) {
    float4 v = *(const float4*)(x8 + (size_t)z * 524288 + (size_t)r * 128 + c4);
    s.x += v.x; s.y += v.y; s.z += v.z; s.w += v.w;
  }
  *(float4*)(xdbl + (size_t)r * 128 + c4) = s;
  if (c4 < 64) {
    ((ushort4*)(dtlow + (size_t)r * 64))[c4 >> 2] =
        make_ushort4(f2b(s.x), f2b(s.y), f2b(s.z), f2b(s.w));
  }
}

// ---------------- chunked selective scan: 64 chunks of 32 ----------------
// Pass A: local scan h0=0, store final state + sum(dt). B staged in LDS.
__global__ __launch_bounds__(256, 4) void scanA_kernel(const ushort* __restrict__ dt,
    const ushort* __restrict__ xs, const float* __restrict__ xdbl,
    const float* __restrict__ A_log, float* __restrict__ FH, float* __restrict__ Sdt) {
  __shared__ float Bsh[32 * 16];
  const int tid = threadIdx.x;
  const int d = blockIdx.x * 256 + tid;
  const int c = blockIdx.y, b = blockIdx.z;
  const int t0 = b * 2048 + c * 32;
  if (tid < 128) {
    const int il = tid >> 2, q = (tid & 3) << 2;
    *(float4*)&Bsh[il * 16 + q] = *(const float4*)(xdbl + (size_t)(t0 + il) * 128 + 64 + q);
  }
  float Ad[16];
  #pragma unroll
  for (int s = 0; s < 16; ++s) Ad[s] = -__expf(A_log[(size_t)d * 16 + s]);
  __syncthreads();
  float h[16];
  #pragma unroll
  for (int s = 0; s < 16; ++s) h[s] = 0.f;
  float sdt = 0.f;
  const ushort* dtp = dt + (size_t)t0 * 2048 + d;
  const ushort* xsp = xs + (size_t)t0 * 2048 + d;
  float dtv = b2f(dtp[0]);
  float xv  = b2f(xsp[0]);
  for (int il = 0; il < 32; ++il) {
    float dtn = 0.f, xn = 0.f;
    if (il < 31) { dtn = b2f(dtp[(il + 1) * 2048]); xn = b2f(xsp[(il + 1) * 2048]); }
    const float dx = dtv * xv;
    sdt += dtv;
    const float* Bv = &Bsh[il * 16];
    #pragma unroll
    for (int s = 0; s < 16; ++s) h[s] = __expf(dtv * Ad[s]) * h[s] + dx * Bv[s];
    dtv = dtn; xv = xn;
  }
  const size_t fo = (((size_t)b * 64 + c) * 2048 + d) * 16;
  #pragma unroll
  for (int q = 0; q < 4; ++q)
    *(float4*)(FH + fo + q * 4) = make_float4(h[q*4], h[q*4+1], h[q*4+2], h[q*4+3]);
  Sdt[((size_t)b * 64 + c) * 2048 + d] = sdt;
}

// Pass B: chunk combine, state-parallel: thread per (b,d,s). In place FH: F -> Hinit.
__global__ __launch_bounds__(256) void scanB_kernel(float* __restrict__ FH,
    const float* __restrict__ Sdt, const float* __restrict__ A_log) {
  const int idx = blockIdx.x * 256 + threadIdx.x;  // 65536 = (b,d,s)
  const int s = idx & 15;
  const int d = (idx >> 4) & 2047;
  const int b = idx >> 15;
  const float Ad = -__expf(A_log[(size_t)d * 16 + s]);
  float H = 0.f;
  #pragma unroll 8
  for (int c = 0; c < 64; ++c) {
    const size_t o = (((size_t)b * 64 + c) * 2048 + d) * 16 + s;
    const float F   = FH[o];
    const float sdt = Sdt[((size_t)b * 64 + c) * 2048 + d];
    FH[o] = H;
    H = __expf(sdt * Ad) * H + F;
  }
}

// Pass C: recompute local scan from initial state; emit gated output. B,C staged in LDS.
__global__ __launch_bounds__(256, 4) void scanC_kernel(const ushort* __restrict__ dt,
    const ushort* __restrict__ xs, const float* __restrict__ xdbl,
    const ushort* __restrict__ xz, const float* __restrict__ A_log,
    const float* __restrict__ Dskip, const float* __restrict__ FH,
    ushort* __restrict__ yg) {
  __shared__ float BCsh[32 * 32];
  const int tid = threadIdx.x;
  const int d = blockIdx.x * 256 + tid;
  const int c = blockIdx.y, b = blockIdx.z;
  const int t0 = b * 2048 + c * 32;
  {
    const int il = tid >> 3, q = (tid & 7) << 2;
    *(float4*)&BCsh[il * 32 + q] = *(const float4*)(xdbl + (size_t)(t0 + il) * 128 + 64 + q);
  }
  float Ad[16];
  #pragma unroll
  for (int s = 0; s < 16; ++s) Ad[s] = -__expf(A_log[(size_t)d * 16 + s]);
  float h[16];
  const size_t ho = (((size_t)b * 64 + c) * 2048 + d) * 16;
  {
    const float4* Hp = (const float4*)(FH + ho);
    float4 H0 = Hp[0], H1 = Hp[1], H2 = Hp[2], H3 = Hp[3];
    h[0]=H0.x; h[1]=H0.y; h[2]=H0.z; h[3]=H0.w;
    h[4]=H1.x; h[5]=H1.y; h[6]=H1.z; h[7]=H1.w;
    h[8]=H2.x; h[9]=H2.y; h[10]=H2.z; h[11]=H2.w;
    h[12]=H3.x; h[13]=H3.y; h[14]=H3.z; h[15]=H3.w;
  }
  __syncthreads();
  const float Dk = Dskip[d];
  const ushort* dtp = dt + (size_t)t0 * 2048 + d;
  const ushort* xsp = xs + (size_t)t0 * 2048 + d;
  const ushort* zp  = xz + (size_t)t0 * 4096 + 2048 + d;
  ushort* ygp = yg + (size_t)t0 * 2048 + d;
  float dtv = b2f(dtp[0]);
  float xv  = b2f(xsp[0]);
  float zv  = b2f(zp[0]);
  for (int il = 0; il < 32; ++il) {
    float dtn = 0.f, xn = 0.f, zn = 0.f;
    if (il < 31) {
      dtn = b2f(dtp[(il + 1) * 2048]);
      xn  = b2f(xsp[(il + 1) * 2048]);
      zn  = b2f(zp[(size_t)(il + 1) * 4096]);
    }
    const float dx = dtv * xv;
    const float* Bv = &BCsh[il * 32];
    const float* Cv = &BCsh[il * 32 + 16];
    float y = 0.f;
    #pragma unroll
    for (int s = 0; s < 16; ++s) {
      h[s] = __expf(dtv * Ad[s]) * h[s] + dx * Bv[s];
      y += h[s] * Cv[s];
    }
    const float g = zv / (1.f + __expf(-zv));
    ygp[il * 2048] = f2b((y + xv * Dk) * g);
    dtv = dtn; xv = xn; zv = zn;
  }
}

// ---------------- launch ----------------
extern "C" void kernel_launch(void* const* d_in, const int* in_sizes, int n_in,
                              void* d_out, int out_size, void* d_ws, size_t ws_size,
                              hipStream_t stream) {
  (void)in_sizes; (void)n_in; (void)out_size; (void)ws_size;
  const float* x       = (const float*)d_in[0];
  const float* ln_w    = (const float*)d_in[1];
  const float* ln_b    = (const float*)d_in[2];
  const float* W_in    = (const float*)d_in[3];
  const float* conv_w  = (const float*)d_in[4];
  const float* conv_b  = (const float*)d_in[5];
  const float* W_xproj = (const float*)d_in[6];
  const float* W_dt    = (const float*)d_in[7];
  const float* b_dt    = (const float*)d_in[8];
  const float* A_log   = (const float*)d_in[9];
  const float* D_skip  = (const float*)d_in[10];
  const float* W_out   = (const float*)d_in[11];
  float* out = (float*)d_out;

  char* ws = (char*)d_ws;
  size_t off = 0;
  auto alloc = [&](size_t bytes) -> void* {
    void* p = ws + off;
    off += (bytes + 255) & ~(size_t)255;
    return p;
  };
  ushort* win_bf   = (ushort*)alloc((size_t)4096 * 1024 * 2);  //  8 MB
  ushort* wout_bf  = (ushort*)alloc((size_t)1024 * 2048 * 2);  //  4 MB
  ushort* wxp_bf   = (ushort*)alloc((size_t)128 * 2048 * 2);   //  0.5 MB
  ushort* wdt_bf   = (ushort*)alloc((size_t)2048 * 64 * 2);    //  0.25 MB
  ushort* xn_bf    = (ushort*)alloc((size_t)4096 * 1024 * 2);  //  8 MB
  ushort* xz_bf    = (ushort*)alloc((size_t)4096 * 4096 * 2);  // 32 MB
  ushort* xs_bf    = (ushort*)alloc((size_t)4096 * 2048 * 2);  // 16 MB
  float*  xdbl     = (float*)alloc((size_t)4096 * 128 * 4);    //  2 MB
  float*  xdbl8    = (float*)alloc((size_t)8 * 4096 * 128 * 4);// 16 MB (aliased: FH after reduce)
  ushort* dtlow_bf = (ushort*)alloc((size_t)4096 * 64 * 2);    //  0.5 MB
  ushort* dtf_bf   = (ushort*)alloc((size_t)4096 * 2048 * 2);  // 16 MB (bf16 dt)
  float*  SdtBuf   = (float*)alloc((size_t)2 * 64 * 2048 * 4); //  1 MB
  ushort* yg_bf    = (ushort*)alloc((size_t)4096 * 2048 * 2);  // 16 MB  (total ~120 MB)
  float*  FH       = xdbl8;  // alias: xdbl8 dead after reduce; FH = 2*64*2048*16 f32 = 16 MB

  prep_weights_kernel<<<6528, 256, 0, stream>>>(W_in, W_out, W_dt, W_xproj,
                                                win_bf, wout_bf, wdt_bf, wxp_bf);
  ln_kernel<<<4096, 256, 0, stream>>>(x, ln_w, ln_b, xn_bf);

  // xz[4096,4096] = xn @ W_in^T   (bf16 out)   K=1024 -> 16 tiles
  gemm_db<1><<<dim3(64, 32, 1), 256, 0, stream>>>(xn_bf, win_bf, nullptr, xz_bf,
                                                  nullptr, 4096, 4096, 1024, 16);
  conv_silu_kernel<<<2048, 256, 0, stream>>>(xz_bf, conv_w, conv_b, xs_bf);

  // x_dbl slices[8][4096][128] = xs @ Wxp^T  (split-K: 8 slices x 4 tiles)
  gemm_db<2><<<dim3(64, 1, 8), 256, 0, stream>>>(xs_bf, wxp_bf, xdbl8, nullptr,
                                                 nullptr, 4096, 128, 2048, 4);
  xdbl_reduce_kernel<<<512, 256, 0, stream>>>(xdbl8, xdbl, dtlow_bf);

  // dt[4096,2048] = softplus(dt_low @ W_dt^T + b_dt)  (bf16 out)  K=64 -> 1 tile
  gemm_db<3><<<dim3(64, 16, 1), 256, 0, stream>>>(dtlow_bf, wdt_bf, nullptr, dtf_bf,
                                                  b_dt, 4096, 2048, 64, 1);

  scanA_kernel<<<dim3(8, 64, 2), 256, 0, stream>>>(dtf_bf, xs_bf, xdbl, A_log, FH, SdtBuf);
  scanB_kernel<<<256, 256, 0, stream>>>(FH, SdtBuf, A_log);
  scanC_kernel<<<dim3(8, 64, 2), 256, 0, stream>>>(dtf_bf, xs_bf, xdbl, xz_bf, A_log, D_skip,
                                                   FH, yg_bf);

  // out[4096,1024] = x + yg @ W_out^T   K=2048 -> 32 tiles
  gemm_db<4><<<dim3(64, 8, 1), 256, 0, stream>>>(yg_bf, wout_bf, out, nullptr, x,
                                                 4096, 1024, 2048, 32);
}

// Round 8
// 289.183 us; speedup vs baseline: 1.5048x; 1.0053x over previous
//
#include <hip/hip_runtime.h>
#include <hip/hip_bf16.h>

// Mamba layer: LN -> in_proj GEMM -> conv+SiLU -> xproj GEMM(splitK) -> dt GEMM+softplus
//              -> chunked selective scan (64 chunks, state-parallel combine) -> gate
//              -> out_proj GEMM + residual.
// GEMM: bf16 MFMA 16x16x32, BM=64/BN=128/BK=64, TRIPLE-buffered LDS with counted
//       s_waitcnt vmcnt(6) (2-deep pipeline, loads span 2 compute phases; T3+T4),
//       XOR-swizzled staging, coalesced epilogue via LDS bounce (stride-132 f32).

typedef __attribute__((ext_vector_type(4))) float f32x4;
typedef __attribute__((ext_vector_type(8))) short s16x8;

static __device__ __forceinline__ float b2f(ushort u) {
  union { float f; unsigned int i; } v; v.i = ((unsigned int)u) << 16; return v.f;
}
static __device__ __forceinline__ ushort f2b(float f) {
  union { __hip_bfloat16 h; ushort u; } v; v.h = __float2bfloat16(f); return v.u;
}

#define GLD16(gp, lp) __builtin_amdgcn_global_load_lds( \
    (const __attribute__((address_space(1))) void*)(gp), \
    (__attribute__((address_space(3))) void*)(lp), 16, 0, 0)

// ---------------- merged weight prep (all f32->bf16 casts in one dispatch) ----------
__global__ void prep_weights_kernel(const float* __restrict__ W_in,
    const float* __restrict__ W_out, const float* __restrict__ W_dt,
    const float* __restrict__ W_xproj, ushort* __restrict__ win,
    ushort* __restrict__ wout, ushort* __restrict__ wdt, ushort* __restrict__ wxp) {
  int i = blockIdx.x * 256 + threadIdx.x;     // float4 index
  if (i < 1048576) {
    float4 v = ((const float4*)W_in)[i];
    ((ushort4*)win)[i] = make_ushort4(f2b(v.x), f2b(v.y), f2b(v.z), f2b(v.w));
    return;
  }
  i -= 1048576;
  if (i < 524288) {
    float4 v = ((const float4*)W_out)[i];
    ((ushort4*)wout)[i] = make_ushort4(f2b(v.x), f2b(v.y), f2b(v.z), f2b(v.w));
    return;
  }
  i -= 524288;
  if (i < 32768) {
    float4 v = ((const float4*)W_dt)[i];
    ((ushort4*)wdt)[i] = make_ushort4(f2b(v.x), f2b(v.y), f2b(v.z), f2b(v.w));
    return;
  }
  i -= 32768;
  if (i < 65536) {
    int e  = i >> 9;
    int k4 = (i & 511) << 2;
    ushort4 o = make_ushort4(0, 0, 0, 0);
    if (e < 96) {
      float4 v = *(const float4*)(W_xproj + (size_t)e * 2048 + k4);
      o = make_ushort4(f2b(v.x), f2b(v.y), f2b(v.z), f2b(v.w));
    }
    ((ushort4*)wxp)[i] = o;
  }
}

// ---------------- layernorm -> bf16 ----------------
__global__ __launch_bounds__(256) void ln_kernel(const float* __restrict__ x,
    const float* __restrict__ w, const float* __restrict__ b, ushort* __restrict__ xn) {
  const int row = blockIdx.x;       // 4096 rows of 1024
  const int tid = threadIdx.x;
  float4 v = ((const float4*)(x + (size_t)row * 1024))[tid];
  float s  = v.x + v.y + v.z + v.w;
  float s2 = v.x*v.x + v.y*v.y + v.z*v.z + v.w*v.w;
  #pragma unroll
  for (int off = 32; off; off >>= 1) { s += __shfl_xor(s, off); s2 += __shfl_xor(s2, off); }
  __shared__ float red[8];
  if ((tid & 63) == 0) { red[tid >> 6] = s; red[(tid >> 6) + 4] = s2; }
  __syncthreads();
  float S  = red[0] + red[1] + red[2] + red[3];
  float S2 = red[4] + red[5] + red[6] + red[7];
  float mu   = S * (1.0f / 1024.0f);
  float var  = S2 * (1.0f / 1024.0f) - mu * mu;
  float rstd = rsqrtf(var + 1e-5f);
  float4 wv = ((const float4*)w)[tid];
  float4 bv = ((const float4*)b)[tid];
  ushort4 o = make_ushort4(
      f2b((v.x - mu) * rstd * wv.x + bv.x),
      f2b((v.y - mu) * rstd * wv.y + bv.y),
      f2b((v.z - mu) * rstd * wv.z + bv.z),
      f2b((v.w - mu) * rstd * wv.w + bv.w));
  ((ushort4*)(xn + (size_t)row * 1024))[tid] = o;
}

// ---------------- bf16 MFMA GEMM: C[M,N] = A[M,K] * B[N,K]^T ----------
// BM=64, BN=128, BK=64. 4 waves 2x2; wave tile 32x64. Triple-buffered LDS,
// counted vmcnt: tile t's 6 loads are the oldest 6 of <=12 outstanding.
// EPI: 1 = store bf16, 2 = store fp32 slice (split-K, slice = blockIdx.z),
//      3 = +bias[col], softplus, store bf16, 4 = residual: Cf[o] = aux[o] + v
template<int EPI>
__global__ __launch_bounds__(256, 2) void gemm_db(
    const ushort* __restrict__ A, const ushort* __restrict__ B,
    float* __restrict__ Cf, ushort* __restrict__ Cb,
    const float* __restrict__ aux,
    int M, int N, int K, int kt_per)
{
  // buffer: A 64x64 bf16 (8KB) + B 128x64 (16KB) = 24KB; x3 = 72KB.
  __shared__ __align__(16) char SM[73728];
  const int tid  = threadIdx.x;
  const int lane = tid & 63;
  const int wid  = tid >> 6;
  const int wr = wid >> 1, wc = wid & 1;
  const int m0 = blockIdx.x * 64, n0 = blockIdx.y * 128;
  const int kt0 = blockIdx.z * kt_per;
  const int nt  = kt_per;

  // staging: lane -> row (tid>>3), 16B slot (tid&7); XOR-swizzled source column.
  const int srow = tid >> 3;                       // 0..31
  const int sxor = ((tid & 7) ^ (srow & 7)) << 3;  // element offset in row
  const ushort* Ag = A + (size_t)(m0 + srow) * K + sxor + (size_t)kt0 * 64;
  const ushort* Bg = B + (size_t)(n0 + srow) * K + sxor + (size_t)kt0 * 64;
  const size_t rstep = (size_t)32 * K;             // 32 rows per GLD round
  char* lds0 = (char*)SM + wid * 1024;             // wave-uniform base

  f32x4 acc[2][4];
  #pragma unroll
  for (int m = 0; m < 2; ++m)
    #pragma unroll
    for (int n = 0; n < 4; ++n)
      acc[m][n] = (f32x4){0.f, 0.f, 0.f, 0.f};

  const int frow = lane & 15;
  const int fk   = (lane >> 4) << 3;   // 0,8,16,24
  const int sw   = (lane & 7) << 3;    // read-side swizzle

#define STAGE(sel, ktv) { \
    const ushort* ag = Ag + (size_t)(ktv) * 64; \
    const ushort* bg = Bg + (size_t)(ktv) * 64; \
    char* ba = lds0 + (sel) * 24576; \
    GLD16(ag,             ba); \
    GLD16(ag + rstep,     ba + 4096); \
    GLD16(bg,             ba + 8192); \
    GLD16(bg + rstep,     ba + 12288); \
    GLD16(bg + 2 * rstep, ba + 16384); \
    GLD16(bg + 3 * rstep, ba + 20480); \
  }

#define COMPUTE(sel) { \
    const ushort* Asb = (const ushort*)((const char*)SM + (sel) * 24576); \
    const ushort* Bsb = Asb + 4096; /* +8192 bytes */ \
    _Pragma("unroll") \
    for (int kk = 0; kk < 2; ++kk) { \
      const int col = (kk * 32 + fk) ^ sw; \
      s16x8 af[2], bf[4]; \
      _Pragma("unroll") \
      for (int m = 0; m < 2; ++m) \
        af[m] = *(const s16x8*)(Asb + (wr * 32 + m * 16 + frow) * 64 + col); \
      _Pragma("unroll") \
      for (int n = 0; n < 4; ++n) \
        bf[n] = *(const s16x8*)(Bsb + (wc * 64 + n * 16 + frow) * 64 + col); \
      _Pragma("unroll") \
      for (int m = 0; m < 2; ++m) \
        _Pragma("unroll") \
        for (int n = 0; n < 4; ++n) \
          acc[m][n] = __builtin_amdgcn_mfma_f32_16x16x32_bf16(af[m], bf[n], acc[m][n], 0, 0, 0); \
    } \
  }

  // ---- 2-deep software pipeline with counted vmcnt ----
  STAGE(0, 0);
  if (nt > 1) STAGE(1, 1);
  int bc = 0;                         // buffer holding tile t
  for (int t = 0; t < nt; ++t) {
    if (t + 1 < nt) { asm volatile("s_waitcnt vmcnt(6)" ::: "memory"); }
    else            { asm volatile("s_waitcnt vmcnt(0)" ::: "memory"); }
    __builtin_amdgcn_s_barrier();     // tile t visible to all; buf (t+2)%3 free
    __builtin_amdgcn_sched_barrier(0);
    if (t + 2 < nt) { int bs = bc + 2; if (bs >= 3) bs -= 3; STAGE(bs, t + 2); }
    COMPUTE(bc);
    if (++bc == 3) bc = 0;
  }
  __syncthreads();                    // all waves done reading LDS; reuse for epilogue

  // ---- coalesced epilogue: 2 phases of 32 rows through LDS (stride 132) ----
  float* epi = (float*)SM;
  const int rl = tid >> 3;              // 0..31
  const int c0 = (tid & 7) << 4;        // 0,16,...,112
  const size_t zoff = (EPI == 2) ? (size_t)blockIdx.z * M * N : 0;
  #pragma unroll
  for (int m = 0; m < 2; ++m) {
    #pragma unroll
    for (int n = 0; n < 4; ++n) {
      const int cl = wc * 64 + n * 16 + (lane & 15);
      #pragma unroll
      for (int j = 0; j < 4; ++j) {
        const int rr = wr * 16 + ((lane >> 4) << 2) + j;
        epi[rr * 132 + cl] = acc[m][n][j];
      }
    }
    __syncthreads();
    const int grow = m0 + ((rl >> 4) << 5) + m * 16 + (rl & 15);
    const int gcol = n0 + c0;
    float v[16];
    #pragma unroll
    for (int q = 0; q < 16; ++q) v[q] = epi[rl * 132 + c0 + q];
    if (EPI == 1) {
      ushort u[16];
      #pragma unroll
      for (int q = 0; q < 16; ++q) u[q] = f2b(v[q]);
      *(int4*)(Cb + (size_t)grow * N + gcol)     = *(int4*)&u[0];
      *(int4*)(Cb + (size_t)grow * N + gcol + 8) = *(int4*)&u[8];
    } else if (EPI == 2) {
      #pragma unroll
      for (int q = 0; q < 4; ++q)
        *(float4*)(Cf + zoff + (size_t)grow * N + gcol + q * 4) = *(float4*)&v[q * 4];
    } else if (EPI == 3) {
      ushort u[16];
      #pragma unroll
      for (int q = 0; q < 4; ++q) {
        float4 bb = *(const float4*)(aux + gcol + q * 4);
        float t0 = v[q*4+0] + bb.x, t1 = v[q*4+1] + bb.y;
        float t2 = v[q*4+2] + bb.z, t3 = v[q*4+3] + bb.w;
        u[q*4+0] = f2b(fmaxf(t0, 0.f) + __logf(1.f + __expf(-fabsf(t0))));
        u[q*4+1] = f2b(fmaxf(t1, 0.f) + __logf(1.f + __expf(-fabsf(t1))));
        u[q*4+2] = f2b(fmaxf(t2, 0.f) + __logf(1.f + __expf(-fabsf(t2))));
        u[q*4+3] = f2b(fmaxf(t3, 0.f) + __logf(1.f + __expf(-fabsf(t3))));
      }
      *(int4*)(Cb + (size_t)grow * N + gcol)     = *(int4*)&u[0];
      *(int4*)(Cb + (size_t)grow * N + gcol + 8) = *(int4*)&u[8];
    } else {
      #pragma unroll
      for (int q = 0; q < 4; ++q) {
        float4 rr2 = *(const float4*)(aux + (size_t)grow * N + gcol + q * 4);
        float4 ov = make_float4(rr2.x + v[q*4+0], rr2.y + v[q*4+1],
                                rr2.z + v[q*4+2], rr2.w + v[q*4+3]);
        *(float4*)(Cf + (size_t)grow * N + gcol + q * 4) = ov;
      }
    }
    __syncthreads();
  }
#undef STAGE
#undef COMPUTE
}

// ---------------- depthwise causal conv1d + SiLU (4 ch x 4 l per thread) ----------
__global__ __launch_bounds__(256) void conv_silu_kernel(const ushort* __restrict__ xz,
    const float* __restrict__ cw, const float* __restrict__ cb, ushort* __restrict__ xs) {
  const int idx = blockIdx.x * 256 + threadIdx.x;  // 524288 = 2 * 512lg * 512d4
  const int d4 = idx & 511;
  const int lg = (idx >> 9) & 511;
  const int b  = idx >> 18;
  const int d  = d4 << 2;
  const int l0 = lg << 2;
  float w[4][4];
  const float* cwd = cw + d * 4;
  #pragma unroll
  for (int j = 0; j < 4; ++j)
    #pragma unroll
    for (int t = 0; t < 4; ++t) w[j][t] = cwd[j * 4 + t];
  const float4 bias = *(const float4*)(cb + d);
  float vin[7][4];
  const size_t base = (size_t)(b * 2048) * 4096 + d;
  #pragma unroll
  for (int j = 0; j < 7; ++j) {
    const int ls = l0 - 3 + j;
    if (ls >= 0) {
      ushort4 xv = *(const ushort4*)(xz + base + (size_t)ls * 4096);
      vin[j][0] = b2f(xv.x); vin[j][1] = b2f(xv.y);
      vin[j][2] = b2f(xv.z); vin[j][3] = b2f(xv.w);
    } else {
      vin[j][0] = vin[j][1] = vin[j][2] = vin[j][3] = 0.f;
    }
  }
  #pragma unroll
  for (int i = 0; i < 4; ++i) {
    float a0 = bias.x, a1 = bias.y, a2 = bias.z, a3 = bias.w;
    #pragma unroll
    for (int t = 0; t < 4; ++t) {
      a0 += vin[i + t][0] * w[0][t];
      a1 += vin[i + t][1] * w[1][t];
      a2 += vin[i + t][2] * w[2][t];
      a3 += vin[i + t][3] * w[3][t];
    }
    ushort4 o;
    o.x = f2b(a0 / (1.f + __expf(-a0)));
    o.y = f2b(a1 / (1.f + __expf(-a1)));
    o.z = f2b(a2 / (1.f + __expf(-a2)));
    o.w = f2b(a3 / (1.f + __expf(-a3)));
    *(ushort4*)(xs + (size_t)(b * 2048 + l0 + i) * 2048 + d) = o;
  }
}

// ---------------- xproj split-K reduce + dtlow cast ----------------
__global__ __launch_bounds__(256) void xdbl_reduce_kernel(const float* __restrict__ x8,
    float* __restrict__ xdbl, ushort* __restrict__ dtlow) {
  const int i = blockIdx.x * 256 + threadIdx.x;  // 131072 = 4096*128/4
  const int r = i >> 5, c4 = (i & 31) << 2;
  float4 s = make_float4(0.f, 0.f, 0.f, 0.f);
  #pragma unroll
  for (int z = 0; z < 8; ++z) {
    float4 v = *(const float4*)(x8 + (size_t)z * 524288 + (size_t)r * 128 + c4);
    s.x += v.x; s.y += v.y; s.z += v.z; s.w += v.w;
  }
  *(float4*)(xdbl + (size_t)r * 128 + c4) = s;
  if (c4 < 64) {
    ((ushort4*)(dtlow + (size_t)r * 64))[c4 >> 2] =
        make_ushort4(f2b(s.x), f2b(s.y), f2b(s.z), f2b(s.w));
  }
}

// ---------------- chunked selective scan: 64 chunks of 32 ----------------
// Pass A: local scan h0=0, store final state + sum(dt). B staged in LDS.
__global__ __launch_bounds__(256, 4) void scanA_kernel(const ushort* __restrict__ dt,
    const ushort* __restrict__ xs, const float* __restrict__ xdbl,
    const float* __restrict__ A_log, float* __restrict__ FH, float* __restrict__ Sdt) {
  __shared__ float Bsh[32 * 16];
  const int tid = threadIdx.x;
  const int d = blockIdx.x * 256 + tid;
  const int c = blockIdx.y, b = blockIdx.z;
  const int t0 = b * 2048 + c * 32;
  if (tid < 128) {
    const int il = tid >> 2, q = (tid & 3) << 2;
    *(float4*)&Bsh[il * 16 + q] = *(const float4*)(xdbl + (size_t)(t0 + il) * 128 + 64 + q);
  }
  float Ad[16];
  #pragma unroll
  for (int s = 0; s < 16; ++s) Ad[s] = -__expf(A_log[(size_t)d * 16 + s]);
  __syncthreads();
  float h[16];
  #pragma unroll
  for (int s = 0; s < 16; ++s) h[s] = 0.f;
  float sdt = 0.f;
  const ushort* dtp = dt + (size_t)t0 * 2048 + d;
  const ushort* xsp = xs + (size_t)t0 * 2048 + d;
  float dtv = b2f(dtp[0]);
  float xv  = b2f(xsp[0]);
  for (int il = 0; il < 32; ++il) {
    float dtn = 0.f, xn = 0.f;
    if (il < 31) { dtn = b2f(dtp[(il + 1) * 2048]); xn = b2f(xsp[(il + 1) * 2048]); }
    const float dx = dtv * xv;
    sdt += dtv;
    const float* Bv = &Bsh[il * 16];
    #pragma unroll
    for (int s = 0; s < 16; ++s) h[s] = __expf(dtv * Ad[s]) * h[s] + dx * Bv[s];
    dtv = dtn; xv = xn;
  }
  const size_t fo = (((size_t)b * 64 + c) * 2048 + d) * 16;
  #pragma unroll
  for (int q = 0; q < 4; ++q)
    *(float4*)(FH + fo + q * 4) = make_float4(h[q*4], h[q*4+1], h[q*4+2], h[q*4+3]);
  Sdt[((size_t)b * 64 + c) * 2048 + d] = sdt;
}

// Pass B: chunk combine, state-parallel: thread per (b,d,s). In place FH: F -> Hinit.
__global__ __launch_bounds__(256) void scanB_kernel(float* __restrict__ FH,
    const float* __restrict__ Sdt, const float* __restrict__ A_log) {
  const int idx = blockIdx.x * 256 + threadIdx.x;  // 65536 = (b,d,s)
  const int s = idx & 15;
  const int d = (idx >> 4) & 2047;
  const int b = idx >> 15;
  const float Ad = -__expf(A_log[(size_t)d * 16 + s]);
  float H = 0.f;
  #pragma unroll 8
  for (int c = 0; c < 64; ++c) {
    const size_t o = (((size_t)b * 64 + c) * 2048 + d) * 16 + s;
    const float F   = FH[o];
    const float sdt = Sdt[((size_t)b * 64 + c) * 2048 + d];
    FH[o] = H;
    H = __expf(sdt * Ad) * H + F;
  }
}

// Pass C: recompute local scan from initial state; emit gated output. B,C staged in LDS.
__global__ __launch_bounds__(256, 4) void scanC_kernel(const ushort* __restrict__ dt,
    const ushort* __restrict__ xs, const float* __restrict__ xdbl,
    const ushort* __restrict__ xz, const float* __restrict__ A_log,
    const float* __restrict__ Dskip, const float* __restrict__ FH,
    ushort* __restrict__ yg) {
  __shared__ float BCsh[32 * 32];
  const int tid = threadIdx.x;
  const int d = blockIdx.x * 256 + tid;
  const int c = blockIdx.y, b = blockIdx.z;
  const int t0 = b * 2048 + c * 32;
  {
    const int il = tid >> 3, q = (tid & 7) << 2;
    *(float4*)&BCsh[il * 32 + q] = *(const float4*)(xdbl + (size_t)(t0 + il) * 128 + 64 + q);
  }
  float Ad[16];
  #pragma unroll
  for (int s = 0; s < 16; ++s) Ad[s] = -__expf(A_log[(size_t)d * 16 + s]);
  float h[16];
  const size_t ho = (((size_t)b * 64 + c) * 2048 + d) * 16;
  {
    const float4* Hp = (const float4*)(FH + ho);
    float4 H0 = Hp[0], H1 = Hp[1], H2 = Hp[2], H3 = Hp[3];
    h[0]=H0.x; h[1]=H0.y; h[2]=H0.z; h[3]=H0.w;
    h[4]=H1.x; h[5]=H1.y; h[6]=H1.z; h[7]=H1.w;
    h[8]=H2.x; h[9]=H2.y; h[10]=H2.z; h[11]=H2.w;
    h[12]=H3.x; h[13]=H3.y; h[14]=H3.z; h[15]=H3.w;
  }
  __syncthreads();
  const float Dk = Dskip[d];
  const ushort* dtp = dt + (size_t)t0 * 2048 + d;
  const ushort* xsp = xs + (size_t)t0 * 2048 + d;
  const ushort* zp  = xz + (size_t)t0 * 4096 + 2048 + d;
  ushort* ygp = yg + (size_t)t0 * 2048 + d;
  float dtv = b2f(dtp[0]);
  float xv  = b2f(xsp[0]);
  float zv  = b2f(zp[0]);
  for (int il = 0; il < 32; ++il) {
    float dtn = 0.f, xn = 0.f, zn = 0.f;
    if (il < 31) {
      dtn = b2f(dtp[(il + 1) * 2048]);
      xn  = b2f(xsp[(il + 1) * 2048]);
      zn  = b2f(zp[(size_t)(il + 1) * 4096]);
    }
    const float dx = dtv * xv;
    const float* Bv = &BCsh[il * 32];
    const float* Cv = &BCsh[il * 32 + 16];
    float y = 0.f;
    #pragma unroll
    for (int s = 0; s < 16; ++s) {
      h[s] = __expf(dtv * Ad[s]) * h[s] + dx * Bv[s];
      y += h[s] * Cv[s];
    }
    const float g = zv / (1.f + __expf(-zv));
    ygp[il * 2048] = f2b((y + xv * Dk) * g);
    dtv = dtn; xv = xn; zv = zn;
  }
}

// ---------------- launch ----------------
extern "C" void kernel_launch(void* const* d_in, const int* in_sizes, int n_in,
                              void* d_out, int out_size, void* d_ws, size_t ws_size,
                              hipStream_t stream) {
  (void)in_sizes; (void)n_in; (void)out_size; (void)ws_size;
  const float* x       = (const float*)d_in[0];
  const float* ln_w    = (const float*)d_in[1];
  const float* ln_b    = (const float*)d_in[2];
  const float* W_in    = (const float*)d_in[3];
  const float* conv_w  = (const float*)d_in[4];
  const float* conv_b  = (const float*)d_in[5];
  const float* W_xproj = (const float*)d_in[6];
  const float* W_dt    = (const float*)d_in[7];
  const float* b_dt    = (const float*)d_in[8];
  const float* A_log   = (const float*)d_in[9];
  const float* D_skip  = (const float*)d_in[10];
  const float* W_out   = (const float*)d_in[11];
  float* out = (float*)d_out;

  char* ws = (char*)d_ws;
  size_t off = 0;
  auto alloc = [&](size_t bytes) -> void* {
    void* p = ws + off;
    off += (bytes + 255) & ~(size_t)255;
    return p;
  };
  ushort* win_bf   = (ushort*)alloc((size_t)4096 * 1024 * 2);  //  8 MB
  ushort* wout_bf  = (ushort*)alloc((size_t)1024 * 2048 * 2);  //  4 MB
  ushort* wxp_bf   = (ushort*)alloc((size_t)128 * 2048 * 2);   //  0.5 MB
  ushort* wdt_bf   = (ushort*)alloc((size_t)2048 * 64 * 2);    //  0.25 MB
  ushort* xn_bf    = (ushort*)alloc((size_t)4096 * 1024 * 2);  //  8 MB
  ushort* xz_bf    = (ushort*)alloc((size_t)4096 * 4096 * 2);  // 32 MB
  ushort* xs_bf    = (ushort*)alloc((size_t)4096 * 2048 * 2);  // 16 MB
  float*  xdbl     = (float*)alloc((size_t)4096 * 128 * 4);    //  2 MB
  float*  xdbl8    = (float*)alloc((size_t)8 * 4096 * 128 * 4);// 16 MB (aliased: FH after reduce)
  ushort* dtlow_bf = (ushort*)alloc((size_t)4096 * 64 * 2);    //  0.5 MB
  ushort* dtf_bf   = (ushort*)alloc((size_t)4096 * 2048 * 2);  // 16 MB (bf16 dt)
  float*  SdtBuf   = (float*)alloc((size_t)2 * 64 * 2048 * 4); //  1 MB
  ushort* yg_bf    = (ushort*)alloc((size_t)4096 * 2048 * 2);  // 16 MB  (total ~120 MB)
  float*  FH       = xdbl8;  // alias: xdbl8 dead after reduce; FH = 2*64*2048*16 f32 = 16 MB

  prep_weights_kernel<<<6528, 256, 0, stream>>>(W_in, W_out, W_dt, W_xproj,
                                                win_bf, wout_bf, wdt_bf, wxp_bf);
  ln_kernel<<<4096, 256, 0, stream>>>(x, ln_w, ln_b, xn_bf);

  // xz[4096,4096] = xn @ W_in^T   (bf16 out)   K=1024 -> 16 tiles
  gemm_db<1><<<dim3(64, 32, 1), 256, 0, stream>>>(xn_bf, win_bf, nullptr, xz_bf,
                                                  nullptr, 4096, 4096, 1024, 16);
  conv_silu_kernel<<<2048, 256, 0, stream>>>(xz_bf, conv_w, conv_b, xs_bf);

  // x_dbl slices[8][4096][128] = xs @ Wxp^T  (split-K: 8 slices x 4 tiles)
  gemm_db<2><<<dim3(64, 1, 8), 256, 0, stream>>>(xs_bf, wxp_bf, xdbl8, nullptr,
                                                 nullptr, 4096, 128, 2048, 4);
  xdbl_reduce_kernel<<<512, 256, 0, stream>>>(xdbl8, xdbl, dtlow_bf);

  // dt[4096,2048] = softplus(dt_low @ W_dt^T + b_dt)  (bf16 out)  K=64 -> 1 tile
  gemm_db<3><<<dim3(64, 16, 1), 256, 0, stream>>>(dtlow_bf, wdt_bf, nullptr, dtf_bf,
                                                  b_dt, 4096, 2048, 64, 1);

  scanA_kernel<<<dim3(8, 64, 2), 256, 0, stream>>>(dtf_bf, xs_bf, xdbl, A_log, FH, SdtBuf);
  scanB_kernel<<<256, 256, 0, stream>>>(FH, SdtBuf, A_log);
  scanC_kernel<<<dim3(8, 64, 2), 256, 0, stream>>>(dtf_bf, xs_bf, xdbl, xz_bf, A_log, D_skip,
                                                   FH, yg_bf);

  // out[4096,1024] = x + yg @ W_out^T   K=2048 -> 32 tiles
  gemm_db<4><<<dim3(64, 8, 1), 256, 0, stream>>>(yg_bf, wout_bf, out, nullptr, x,
                                                 4096, 1024, 2048, 32);
}